// Round 4
// baseline (250.611 us; speedup 1.0000x reference)
//
#include <hip/hip_runtime.h>
#include <hip/hip_bf16.h>
#include <cstdint>

typedef unsigned short u16;
typedef __bf16 bf16_t;
typedef __bf16 bf16x8 __attribute__((ext_vector_type(8)));
typedef float f32x4 __attribute__((ext_vector_type(4)));

#define DM   512
#define DFF  2048
#define NEXP 8

__device__ __forceinline__ u16 f2bf(float f) {
  bf16_t b = (bf16_t)f;
  return __builtin_bit_cast(u16, b);
}
__device__ __forceinline__ uint32_t pack_bf2(float lo, float hi) {
  return (uint32_t)f2bf(lo) | ((uint32_t)f2bf(hi) << 16);
}
__device__ __forceinline__ float gelu_tanh(float x) {
  float x3 = x * x * x;
  float z = 0.7978845608028654f * (x + 0.044715f * x3);
  float az = fabsf(z);
  float e = __expf(2.0f * az);
  float t = 1.0f - 2.0f / (e + 1.0f);
  t = copysignf(t, z);
  return 0.5f * x * (1.0f + t);
}
__device__ __forceinline__ void async16(const u16* g, u16* l) {
  __builtin_amdgcn_global_load_lds((const __attribute__((address_space(1))) void*)g,
                                   (__attribute__((address_space(3))) void*)l, 16, 0, 0);
}

// ---------- transpose + f32->bf16 convert: src [E][R][C] f32 -> dst [E][C][R] bf16
__global__ void k_transpose_cvt(const float* __restrict__ src, u16* __restrict__ dst,
                                int R, int C) {
  __shared__ u16 tile[64][66];
  int e = blockIdx.y;
  int tilesC = C >> 6;
  int bR = (blockIdx.x / tilesC) << 6;
  int bC = (blockIdx.x % tilesC) << 6;
  const float* s = src + (size_t)e * R * C;
  u16* d = dst + (size_t)e * R * C;
  int rr = threadIdx.x >> 4;
  int cc = (threadIdx.x & 15) << 2;
#pragma unroll
  for (int i = 0; i < 4; ++i) {
    int r = (i << 4) + rr;
    float4 v = *(const float4*)(s + (size_t)(bR + r) * C + bC + cc);
    *(uint32_t*)&tile[r][cc]     = pack_bf2(v.x, v.y);
    *(uint32_t*)&tile[r][cc + 2] = pack_bf2(v.z, v.w);
  }
  __syncthreads();
  int c0 = threadIdx.x >> 5;
  int j  = (threadIdx.x & 31) << 1;
#pragma unroll
  for (int i = 0; i < 8; ++i) {
    int c = (i << 3) + c0;
    uint32_t v = (uint32_t)tile[j][c] | ((uint32_t)tile[j + 1][c] << 16);
    *(uint32_t*)(&d[(size_t)(bC + c) * R + bR + j]) = v;
  }
}

// ---------- router: one wave per token
__global__ void k_router(const float* __restrict__ x, const float* __restrict__ Wr,
                         const float* __restrict__ br, int* __restrict__ sel_idx,
                         float* __restrict__ sel_w, int Ntok) {
  int wid = threadIdx.x >> 6;
  int lane = threadIdx.x & 63;
  int tok = (blockIdx.x << 2) + wid;
  if (tok >= Ntok) return;
  const float4* xr = (const float4*)(x + (size_t)tok * DM);
  float4 x0 = xr[lane * 2], x1 = xr[lane * 2 + 1];
  float logit[NEXP];
#pragma unroll
  for (int e = 0; e < NEXP; ++e) {
    const float4* wr = (const float4*)(Wr + e * DM);
    float4 w0 = wr[lane * 2], w1 = wr[lane * 2 + 1];
    float p = x0.x * w0.x + x0.y * w0.y + x0.z * w0.z + x0.w * w0.w
            + x1.x * w1.x + x1.y * w1.y + x1.z * w1.z + x1.w * w1.w;
#pragma unroll
    for (int off = 32; off; off >>= 1) p += __shfl_xor(p, off, 64);
    logit[e] = p + br[e];
  }
  if (lane == 0) {
    float mx = logit[0];
#pragma unroll
    for (int e = 1; e < NEXP; ++e) mx = fmaxf(mx, logit[e]);
    float pr[NEXP];
#pragma unroll
    for (int e = 0; e < NEXP; ++e) pr[e] = __expf(logit[e] - mx);
    int i0 = 0;
#pragma unroll
    for (int e = 1; e < NEXP; ++e) if (pr[e] > pr[i0]) i0 = e;
    int i1 = -1;
#pragma unroll
    for (int e = 0; e < NEXP; ++e) {
      if (e == i0) continue;
      if (i1 < 0 || pr[e] > pr[i1]) i1 = e;
    }
    float s2 = pr[i0] + pr[i1];
    sel_idx[tok * 2]     = i0;
    sel_idx[tok * 2 + 1] = i1;
    sel_w[tok * 2]       = pr[i0] / s2;
    sel_w[tok * 2 + 1]   = pr[i1] / s2;
  }
}

// ---------- scatter (1 block, ballot-based), 256-row tile granularity
__global__ void k_scatter(const int* __restrict__ sel_idx, const float* __restrict__ sel_w,
                          int npairs, int* __restrict__ row_token, float* __restrict__ row_w,
                          int* __restrict__ pos_of, int* __restrict__ tileMeta,
                          int* __restrict__ gMeta) {
  __shared__ int cnt[NEXP], offs[NEXP], cur[NEXP];
  int tid = threadIdx.x;
  int lane = tid & 63;
  if (tid < NEXP) { cnt[tid] = 0; cur[tid] = 0; }
  __syncthreads();
  for (int p = tid; p < npairs; p += blockDim.x) {
    int e = sel_idx[p];
#pragma unroll
    for (int ex = 0; ex < NEXP; ++ex) {
      unsigned long long m = __ballot(e == ex);
      if (lane == 0 && m) atomicAdd(&cnt[ex], __popcll(m));
    }
  }
  __syncthreads();
  if (tid == 0) {
    int o = 0, nmt = 0;
    for (int e = 0; e < NEXP; ++e) {
      offs[e] = o;
      int c = cnt[e];
      int nt = (c + 255) >> 8;
      for (int t = 0; t < nt; ++t) {
        tileMeta[nmt * 3 + 0] = o + t * 256;
        tileMeta[nmt * 3 + 1] = o + c;
        tileMeta[nmt * 3 + 2] = e;
        ++nmt;
      }
      o += c;
    }
    gMeta[0] = nmt;
  }
  __syncthreads();
  for (int p = tid; p < npairs; p += blockDim.x) {
    int e = sel_idx[p];
    int pos = 0;
#pragma unroll
    for (int ex = 0; ex < NEXP; ++ex) {
      unsigned long long m = __ballot(e == ex);
      if (m) {
        int leader = __ffsll((long long)m) - 1;
        int base = 0;
        if (lane == leader) base = atomicAdd(&cur[ex], __popcll(m));
        base = __shfl(base, leader, 64);
        if (e == ex)
          pos = offs[ex] + base + __popcll(m & ((1ull << lane) - 1ull));
      }
    }
    row_token[pos] = p >> 1;
    row_w[pos] = sel_w[p];
    pos_of[p] = pos;
  }
}

// ---------- gather selected token rows -> bf16
__global__ void k_gather(const float* __restrict__ x, const int* __restrict__ row_token,
                         u16* __restrict__ Xg, int npairs) {
  int pos = (blockIdx.x << 2) + (threadIdx.x >> 6);
  int lane = threadIdx.x & 63;
  if (pos >= npairs) return;
  int tok = row_token[pos];
  const float4* src = (const float4*)(x + (size_t)tok * DM);
  float4 a = src[lane * 2], b = src[lane * 2 + 1];
  uint4 o;
  o.x = pack_bf2(a.x, a.y);
  o.y = pack_bf2(a.z, a.w);
  o.z = pack_bf2(b.x, b.y);
  o.w = pack_bf2(b.z, b.w);
  ((uint4*)(Xg + (size_t)pos * DM))[lane] = o;
}

// ---------- 256-row grouped GEMM, 512 threads / 8 waves, dbuf counted-vmcnt pipeline
// A: [npairs][KTOT] bf16 (+split*KCH)  BT: [E][NFULL][KTOT] bf16  Out: bf16, split offset pstride
// LDS buffer layout (per K-tile buf): A [ks][256][64B] (32KB) then B [ks][BN][64B].
template <int BN, int WN, int NFULL, int KTOT, int NSPLIT, bool GELU, bool SCALE>
__launch_bounds__(512)
__global__ void k_gemm256(const u16* __restrict__ A, const u16* __restrict__ BT,
                          const float* __restrict__ bias, const float* __restrict__ row_w,
                          u16* __restrict__ Out, size_t pstride,
                          const int* __restrict__ tileMeta, const int* __restrict__ gMeta,
                          int maxmt) {
  constexpr int BM = 256;
  constexpr int WM = 8 / WN;
  constexpr int MI = BM / (WM * 16);
  constexpr int NI = BN / (WN * 16);
  constexpr int NTN = NFULL / BN;
  constexpr int KCH = KTOT / NSPLIT;
  constexpr int NK = KCH / 64;
  constexpr int BUFB = (BM + BN) * 128;    // bytes per K-tile double-buffer half
  constexpr int LA = 4;                    // A staging instrs per tile (4 x 8KB)
  constexpr int LB = (BN * 128) / 8192;    // B staging instrs per tile
  constexpr int IPH = BN / 128;            // B instrs per k-half

  __shared__ __align__(16) char smem[2 * BUFB];

  int NB = gridDim.x;
  int bid = blockIdx.x;
  int wg = ((NB & 7) == 0) ? ((bid & 7) * (NB >> 3) + (bid >> 3)) : bid;
  int nt = wg % NTN;
  int rem = wg / NTN;
  int mt = rem % maxmt;
  int split = rem / maxmt;
  if (mt >= gMeta[0]) return;
  int posStart = tileMeta[mt * 3 + 0];
  int segEnd   = tileMeta[mt * 3 + 1];
  int e        = tileMeta[mt * 3 + 2];

  int tid = threadIdx.x, lane = tid & 63, wid = tid >> 6;
  int wm = wid / WN, wn = wid % WN;

  const u16* Ab = A + (size_t)split * KCH;
  const u16* Bb = BT + ((size_t)e * NFULL + (size_t)nt * BN) * KTOT + (size_t)split * KCH;

  // staging source pointers (pre-swizzled global source, linear LDS dest)
  int trow = tid >> 2, tc = tid & 3;
  const u16* aP[LA];
  const u16* bP[LB];
#pragma unroll
  for (int a = 0; a < LA; ++a) {
    int ks = a >> 1, r = ((a & 1) << 7) + trow;
    int g = posStart + r;
    if (g >= segEnd) g = segEnd - 1;
    aP[a] = Ab + (size_t)g * KTOT + ks * 32 + ((tc ^ (r & 3)) << 3);
  }
#pragma unroll
  for (int b = 0; b < LB; ++b) {
    int ks = b / IPH, r = (b % IPH) * 128 + trow;
    bP[b] = Bb + (size_t)r * KTOT + ks * 32 + ((tc ^ (r & 3)) << 3);
  }

  auto stage = [&](int t, int buf) {
    char* dst = smem + buf * BUFB;
#pragma unroll
    for (int a = 0; a < LA; ++a)
      async16(aP[a] + t * 64, (u16*)(dst + a * 8192 + tid * 16));
#pragma unroll
    for (int b = 0; b < LB; ++b)
      async16(bP[b] + t * 64, (u16*)(dst + 32768 + b * 8192 + tid * 16));
  };

  f32x4 acc[MI][NI] = {};

  stage(0, 0);
  stage(1, 1);
#pragma unroll 1
  for (int t = 0; t < NK; ++t) {
    if (t == NK - 1)            asm volatile("s_waitcnt vmcnt(0)" ::: "memory");
    else if constexpr (BN == 256) asm volatile("s_waitcnt vmcnt(8)" ::: "memory");
    else                        asm volatile("s_waitcnt vmcnt(6)" ::: "memory");
    __builtin_amdgcn_s_barrier();
    const char* base = smem + (t & 1) * BUFB;
#pragma unroll
    for (int ks = 0; ks < 2; ++ks) {
      bf16x8 av[MI], bv[NI];
#pragma unroll
      for (int mi = 0; mi < MI; ++mi) {
        int r = wm * (MI * 16) + mi * 16 + (lane & 15);
        av[mi] = *(const bf16x8*)(base + ks * 16384 + r * 64 +
                                  (((lane >> 4) << 4) ^ ((r & 3) << 4)));
      }
#pragma unroll
      for (int ni = 0; ni < NI; ++ni) {
        int c = wn * (NI * 16) + ni * 16 + (lane & 15);
        bv[ni] = *(const bf16x8*)(base + 32768 + ks * (BN * 64) + c * 64 +
                                  (((lane >> 4) << 4) ^ ((c & 3) << 4)));
      }
      __builtin_amdgcn_s_setprio(1);
#pragma unroll
      for (int mi = 0; mi < MI; ++mi)
#pragma unroll
        for (int ni = 0; ni < NI; ++ni)
          acc[mi][ni] = __builtin_amdgcn_mfma_f32_16x16x32_bf16(av[mi], bv[ni], acc[mi][ni], 0, 0, 0);
      __builtin_amdgcn_s_setprio(0);
    }
    __builtin_amdgcn_s_barrier();
    if (t + 2 < NK) stage(t + 2, t & 1);
  }

  // epilogue: frags -> LDS (64KB chunk, XOR-swizzled) -> coalesced 16B stores
  constexpr int CR  = 65536 / (BN * 2);   // rows per chunk (128 or 256)
  constexpr int NCH = BM / CR;
  const float* biasE = bias + (size_t)e * NFULL;
  u16* OutS = Out + (size_t)split * pstride;
#pragma unroll
  for (int ch = 0; ch < NCH; ++ch) {
    if (ch) __syncthreads();
    if ((wm * (MI * 16)) / CR == ch) {
#pragma unroll
      for (int mi = 0; mi < MI; ++mi) {
#pragma unroll
        for (int j = 0; j < 4; ++j) {
          int r = wm * (MI * 16) + mi * 16 + ((lane >> 4) << 2) + j;
          int rl = r - ch * CR;
          int m = posStart + r;
          int mc = m < segEnd ? m : segEnd - 1;
          float w = 1.0f;
          if constexpr (SCALE) w = row_w[mc];
#pragma unroll
          for (int ni = 0; ni < NI; ++ni) {
            int c = wn * (NI * 16) + ni * 16 + (lane & 15);
            float v = acc[mi][ni][j];
            if (split == 0) v += biasE[nt * BN + c];
            if constexpr (GELU) v = gelu_tanh(v);
            if constexpr (SCALE) v *= w;
            *(u16*)(smem + rl * (BN * 2) + ((c * 2) ^ ((rl & 7) << 4))) = f2bf(v);
          }
        }
      }
    }
    __syncthreads();
    constexpr int TPR = (BN * 2) / 128;   // threads per row
    int rl = tid / TPR, cs0 = (tid % TPR) * 128;
    int m = posStart + ch * CR + rl;
    if (m < segEnd) {
      uint4* dst = (uint4*)(OutS + (size_t)m * NFULL + nt * BN + (cs0 >> 1));
#pragma unroll
      for (int i = 0; i < 8; ++i) {
        int cb = cs0 + i * 16;
        dst[i] = *(const uint4*)(smem + rl * (BN * 2) + (cb ^ ((rl & 7) << 4)));
      }
    }
  }
}

// ---------- combine: out[tok] = sum over {split0,1} x {pos0,pos1} of bf16 partials
__global__ void k_combine(const u16* __restrict__ P, size_t pstride,
                          const int* __restrict__ pos_of, float* __restrict__ out, int Ntok) {
  int tok = (blockIdx.x << 2) + (threadIdx.x >> 6);
  int lane = threadIdx.x & 63;
  if (tok >= Ntok) return;
  int p0 = pos_of[tok * 2], p1 = pos_of[tok * 2 + 1];
  bf16x8 a0 = ((const bf16x8*)(P + (size_t)p0 * DM))[lane];
  bf16x8 a1 = ((const bf16x8*)(P + pstride + (size_t)p0 * DM))[lane];
  bf16x8 b0 = ((const bf16x8*)(P + (size_t)p1 * DM))[lane];
  bf16x8 b1 = ((const bf16x8*)(P + pstride + (size_t)p1 * DM))[lane];
  float4 o0, o1;
  o0.x = (float)a0[0] + (float)a1[0] + (float)b0[0] + (float)b1[0];
  o0.y = (float)a0[1] + (float)a1[1] + (float)b0[1] + (float)b1[1];
  o0.z = (float)a0[2] + (float)a1[2] + (float)b0[2] + (float)b1[2];
  o0.w = (float)a0[3] + (float)a1[3] + (float)b0[3] + (float)b1[3];
  o1.x = (float)a0[4] + (float)a1[4] + (float)b0[4] + (float)b1[4];
  o1.y = (float)a0[5] + (float)a1[5] + (float)b0[5] + (float)b1[5];
  o1.z = (float)a0[6] + (float)a1[6] + (float)b0[6] + (float)b1[6];
  o1.w = (float)a0[7] + (float)a1[7] + (float)b0[7] + (float)b1[7];
  float4* o = (float4*)(out + (size_t)tok * DM + lane * 8);
  o[0] = o0;
  o[1] = o1;
}

extern "C" void kernel_launch(void* const* d_in, const int* in_sizes, int n_in,
                              void* d_out, int out_size, void* d_ws, size_t ws_size,
                              hipStream_t stream) {
  const float* x  = (const float*)d_in[0];
  const float* Wr = (const float*)d_in[1];
  const float* br = (const float*)d_in[2];
  const float* W1 = (const float*)d_in[3];
  const float* b1 = (const float*)d_in[4];
  const float* W2 = (const float*)d_in[5];
  const float* b2 = (const float*)d_in[6];
  float* out = (float*)d_out;

  int Ntok = in_sizes[0] / DM;         // 4096
  int npairs = Ntok * 2;               // 8192
  int maxmt = npairs / 256 + NEXP;     // 40
  size_t pstride = (size_t)npairs * DM;  // u16 elements per split

  char* p = (char*)d_ws;
  u16* W1T = (u16*)p;  p += (size_t)NEXP * DFF * DM * 2;
  u16* W2T = (u16*)p;  p += (size_t)NEXP * DM * DFF * 2;
  u16* Xg  = (u16*)p;  p += (size_t)npairs * DM * 2;
  u16* H   = (u16*)p;  p += (size_t)npairs * DFF * 2;
  u16* Part = (u16*)p; p += 2 * pstride * 2;          // [2][npairs][DM] bf16
  int* sel_idx   = (int*)p;   p += (size_t)npairs * 4;
  float* sel_w   = (float*)p; p += (size_t)npairs * 4;
  int* pos_of    = (int*)p;   p += (size_t)npairs * 4;
  int* row_token = (int*)p;   p += (size_t)npairs * 4;
  float* row_w   = (float*)p; p += (size_t)npairs * 4;
  int* tileMeta  = (int*)p;   p += (size_t)(maxmt * 3 + 16) * 4;
  int* gMeta     = (int*)p;   p += 64;

  k_transpose_cvt<<<dim3((DM / 64) * (DFF / 64), NEXP), 256, 0, stream>>>(W1, W1T, DM, DFF);
  k_transpose_cvt<<<dim3((DFF / 64) * (DM / 64), NEXP), 256, 0, stream>>>(W2, W2T, DFF, DM);
  k_router<<<dim3((Ntok + 3) / 4), 256, 0, stream>>>(x, Wr, br, sel_idx, sel_w, Ntok);
  k_scatter<<<dim3(1), 1024, 0, stream>>>(sel_idx, sel_w, npairs, row_token, row_w,
                                          pos_of, tileMeta, gMeta);
  k_gather<<<dim3(npairs / 4), 256, 0, stream>>>(x, row_token, Xg, npairs);
  // GEMM1: H[npairs x 2048] = gelu(Xg * W1T + b1), BM=256 BN=256, no split
  k_gemm256<256, 4, DFF, DM, 1, true, false>
      <<<dim3(maxmt * (DFF / 256)), 512, 0, stream>>>(
          Xg, W1T, b1, nullptr, H, 0, tileMeta, gMeta, maxmt);
  // GEMM2: Part[s][npairs x 512] = (H_s * W2T_s + (s==0)*b2) * row_w, BM=256 BN=128, split-K=2
  k_gemm256<128, 2, DM, DFF, 2, false, true>
      <<<dim3(maxmt * (DM / 128) * 2), 512, 0, stream>>>(
          H, W2T, b2, row_w, Part, pstride, tileMeta, gMeta, maxmt);
  k_combine<<<dim3(Ntok / 4), 256, 0, stream>>>(Part, pstride, pos_of, out, Ntok);
}

// Round 6
// 191.604 us; speedup vs baseline: 1.3080x; 1.3080x over previous
//
#include <hip/hip_runtime.h>
#include <hip/hip_bf16.h>
#include <cstdint>

typedef unsigned short u16;
typedef __bf16 bf16_t;
typedef __bf16 bf16x8 __attribute__((ext_vector_type(8)));
typedef float f32x4 __attribute__((ext_vector_type(4)));

#define DM   512
#define DFF  2048
#define NEXP 8

__device__ __forceinline__ u16 f2bf(float f) {
  bf16_t b = (bf16_t)f;
  return __builtin_bit_cast(u16, b);
}
__device__ __forceinline__ uint32_t pack_bf2(float lo, float hi) {
  return (uint32_t)f2bf(lo) | ((uint32_t)f2bf(hi) << 16);
}
__device__ __forceinline__ float gelu_tanh(float x) {
  float x3 = x * x * x;
  float z = 0.7978845608028654f * (x + 0.044715f * x3);
  float az = fabsf(z);
  float e = __expf(2.0f * az);
  float t = 1.0f - 2.0f / (e + 1.0f);
  t = copysignf(t, z);
  return 0.5f * x * (1.0f + t);
}
__device__ __forceinline__ void async16(const u16* g, u16* l) {
  __builtin_amdgcn_global_load_lds((const __attribute__((address_space(1))) void*)g,
                                   (__attribute__((address_space(3))) void*)l, 16, 0, 0);
}

// ---------- transpose tile body: src [R][C] f32 (+e offset) -> dst [C][R] bf16
__device__ __forceinline__ void transpose_tile(const float* __restrict__ s,
                                               u16* __restrict__ d, int R, int C,
                                               int tileIdx) {
  __shared__ u16 tile[64][66];
  int tilesC = C >> 6;
  int bR = (tileIdx / tilesC) << 6;
  int bC = (tileIdx % tilesC) << 6;
  int rr = threadIdx.x >> 4;
  int cc = (threadIdx.x & 15) << 2;
#pragma unroll
  for (int i = 0; i < 4; ++i) {
    int r = (i << 4) + rr;
    float4 v = *(const float4*)(s + (size_t)(bR + r) * C + bC + cc);
    *(uint32_t*)&tile[r][cc]     = pack_bf2(v.x, v.y);
    *(uint32_t*)&tile[r][cc + 2] = pack_bf2(v.z, v.w);
  }
  __syncthreads();
  int c0 = threadIdx.x >> 5;
  int j  = (threadIdx.x & 31) << 1;
#pragma unroll
  for (int i = 0; i < 8; ++i) {
    int c = (i << 3) + c0;
    uint32_t v = (uint32_t)tile[j][c] | ((uint32_t)tile[j + 1][c] << 16);
    *(uint32_t*)(&d[(size_t)(bC + c) * R + bR + j]) = v;
  }
}

// ---------- fused prep: W1 transpose | W2 transpose | router
__global__ void k_prep(const float* __restrict__ W1, u16* __restrict__ W1T,
                       const float* __restrict__ W2, u16* __restrict__ W2T,
                       const float* __restrict__ x, const float* __restrict__ Wr,
                       const float* __restrict__ br, int* __restrict__ sel_idx,
                       float* __restrict__ sel_w, int Ntok) {
  int b = blockIdx.x;
  if (b < 2048) {
    int e = b >> 8, t = b & 255;
    transpose_tile(W1 + (size_t)e * DM * DFF, W1T + (size_t)e * DM * DFF, DM, DFF, t);
    return;
  }
  if (b < 4096) {
    int e = (b - 2048) >> 8, t = (b - 2048) & 255;
    transpose_tile(W2 + (size_t)e * DFF * DM, W2T + (size_t)e * DFF * DM, DFF, DM, t);
    return;
  }
  int rb = b - 4096;
  int wid = threadIdx.x >> 6;
  int lane = threadIdx.x & 63;
  int tok = (rb << 2) + wid;
  if (tok >= Ntok) return;
  const float4* xr = (const float4*)(x + (size_t)tok * DM);
  float4 x0 = xr[lane * 2], x1 = xr[lane * 2 + 1];
  float logit[NEXP];
#pragma unroll
  for (int e = 0; e < NEXP; ++e) {
    const float4* wr = (const float4*)(Wr + e * DM);
    float4 w0 = wr[lane * 2], w1 = wr[lane * 2 + 1];
    float p = x0.x * w0.x + x0.y * w0.y + x0.z * w0.z + x0.w * w0.w
            + x1.x * w1.x + x1.y * w1.y + x1.z * w1.z + x1.w * w1.w;
#pragma unroll
    for (int off = 32; off; off >>= 1) p += __shfl_xor(p, off, 64);
    logit[e] = p + br[e];
  }
  if (lane == 0) {
    float mx = logit[0];
#pragma unroll
    for (int e = 1; e < NEXP; ++e) mx = fmaxf(mx, logit[e]);
    float pr[NEXP];
#pragma unroll
    for (int e = 0; e < NEXP; ++e) pr[e] = __expf(logit[e] - mx);
    int i0 = 0;
#pragma unroll
    for (int e = 1; e < NEXP; ++e) if (pr[e] > pr[i0]) i0 = e;
    int i1 = -1;
#pragma unroll
    for (int e = 0; e < NEXP; ++e) {
      if (e == i0) continue;
      if (i1 < 0 || pr[e] > pr[i1]) i1 = e;
    }
    float s2 = pr[i0] + pr[i1];
    sel_idx[tok * 2]     = i0;
    sel_idx[tok * 2 + 1] = i1;
    sel_w[tok * 2]       = pr[i0] / s2;
    sel_w[tok * 2 + 1]   = pr[i1] / s2;
  }
}

// ---------- scatter (1 block, ballot-based), 256-row tile granularity
__global__ void k_scatter(const int* __restrict__ sel_idx, const float* __restrict__ sel_w,
                          int npairs, int* __restrict__ row_token, float* __restrict__ row_w,
                          int* __restrict__ pos_of, int* __restrict__ tileMeta,
                          int* __restrict__ gMeta) {
  __shared__ int cnt[NEXP], offs[NEXP], cur[NEXP];
  int tid = threadIdx.x;
  int lane = tid & 63;
  if (tid < NEXP) { cnt[tid] = 0; cur[tid] = 0; }
  __syncthreads();
  for (int p = tid; p < npairs; p += blockDim.x) {
    int e = sel_idx[p];
#pragma unroll
    for (int ex = 0; ex < NEXP; ++ex) {
      unsigned long long m = __ballot(e == ex);
      if (lane == 0 && m) atomicAdd(&cnt[ex], __popcll(m));
    }
  }
  __syncthreads();
  if (tid == 0) {
    int o = 0, nmt = 0;
    for (int e = 0; e < NEXP; ++e) {
      offs[e] = o;
      int c = cnt[e];
      int nt = (c + 255) >> 8;
      for (int t = 0; t < nt; ++t) {
        tileMeta[nmt * 3 + 0] = o + t * 256;
        tileMeta[nmt * 3 + 1] = o + c;
        tileMeta[nmt * 3 + 2] = e;
        ++nmt;
      }
      o += c;
    }
    gMeta[0] = nmt;
  }
  __syncthreads();
  for (int p = tid; p < npairs; p += blockDim.x) {
    int e = sel_idx[p];
    int pos = 0;
#pragma unroll
    for (int ex = 0; ex < NEXP; ++ex) {
      unsigned long long m = __ballot(e == ex);
      if (m) {
        int leader = __ffsll((long long)m) - 1;
        int base = 0;
        if (lane == leader) base = atomicAdd(&cur[ex], __popcll(m));
        base = __shfl(base, leader, 64);
        if (e == ex)
          pos = offs[ex] + base + __popcll(m & ((1ull << lane) - 1ull));
      }
    }
    row_token[pos] = p >> 1;
    row_w[pos] = sel_w[p];
    pos_of[p] = pos;
  }
}

// ---------- gather selected token rows -> bf16
__global__ void k_gather(const float* __restrict__ x, const int* __restrict__ row_token,
                         u16* __restrict__ Xg, int npairs) {
  int pos = (blockIdx.x << 2) + (threadIdx.x >> 6);
  int lane = threadIdx.x & 63;
  if (pos >= npairs) return;
  int tok = row_token[pos];
  const float4* src = (const float4*)(x + (size_t)tok * DM);
  float4 a = src[lane * 2], b = src[lane * 2 + 1];
  uint4 o;
  o.x = pack_bf2(a.x, a.y);
  o.y = pack_bf2(a.z, a.w);
  o.z = pack_bf2(b.x, b.y);
  o.w = pack_bf2(b.z, b.w);
  ((uint4*)(Xg + (size_t)pos * DM))[lane] = o;
}

// ---------- 256x256 grouped GEMM, 512 thr / 8 waves (2Mx4N), BK=32,
// 4-slot LDS ring (4 x 32KB), stage-lead-2, counted vmcnt, 1 barrier/K-tile.
// A: [npairs][KTOT] bf16 (+split*KCH)  BT: [E][NFULL][KTOT] bf16
// Out: bf16 [NSPLIT][npairs][NFULL] (split stride pstride u16 elems)
template <int NFULL, int KTOT, int NSPLIT, bool GELU, bool SCALE>
__launch_bounds__(512, 2)
__global__ void k_gemm256(const u16* __restrict__ A, const u16* __restrict__ BT,
                          const float* __restrict__ bias, const float* __restrict__ row_w,
                          u16* __restrict__ Out, size_t pstride,
                          const int* __restrict__ tileMeta, const int* __restrict__ gMeta,
                          int maxmt) {
  constexpr int NTN = NFULL / 256;
  constexpr int KCH = KTOT / NSPLIT;
  constexpr int NK  = KCH / 32;

  __shared__ __align__(16) char smem[131072];  // slot s: A at s*32768 (16KB), B at +16384

  int NB = gridDim.x;
  int bid = blockIdx.x;
  int wg = ((NB & 7) == 0) ? ((bid & 7) * (NB >> 3) + (bid >> 3)) : bid;  // XCD chunking
  int nt = wg % NTN;
  int rem = wg / NTN;
  int mt = rem % maxmt;
  int split = rem / maxmt;
  if (mt >= gMeta[0]) return;
  int posStart = tileMeta[mt * 3 + 0];
  int segEnd   = tileMeta[mt * 3 + 1];
  int e        = tileMeta[mt * 3 + 2];

  int tid = threadIdx.x, lane = tid & 63, wid = tid >> 6;
  int wm = wid >> 2, wn = wid & 3;   // 2 x 4 waves; wave tile 128 x 64

  const u16* Ab = A + (size_t)split * KCH;
  const u16* Bb = BT + ((size_t)e * NFULL + (size_t)nt * 256) * KTOT + (size_t)split * KCH;

  // staging sources: instr covers LDS rows i*128 + tid/4, chunk tid&3 (16B of 64B row).
  // pre-swizzled source chunk = c ^ (row&3); LDS dest linear (gload_lds requirement).
  int trow = tid >> 2, tc = tid & 3;
  const u16 *aP0, *aP1, *bP0, *bP1;
  {
    int r0 = trow, r1 = 128 + trow;
    int g0 = posStart + r0; if (g0 >= segEnd) g0 = segEnd - 1;
    int g1 = posStart + r1; if (g1 >= segEnd) g1 = segEnd - 1;
    aP0 = Ab + (size_t)g0 * KTOT + ((tc ^ (r0 & 3)) << 3);
    aP1 = Ab + (size_t)g1 * KTOT + ((tc ^ (r1 & 3)) << 3);
    bP0 = Bb + (size_t)r0 * KTOT + ((tc ^ (r0 & 3)) << 3);
    bP1 = Bb + (size_t)r1 * KTOT + ((tc ^ (r1 & 3)) << 3);
  }

  auto stage = [&](int t, int slot) {
    char* dst = smem + slot * 32768;
    async16(aP0 + t * 32, (u16*)(dst + tid * 16));
    async16(aP1 + t * 32, (u16*)(dst + 8192 + tid * 16));
    async16(bP0 + t * 32, (u16*)(dst + 16384 + tid * 16));
    async16(bP1 + t * 32, (u16*)(dst + 24576 + tid * 16));
  };

  // fragment byte offsets within a slot (swizzled reads: chunk kq ^ (r&3))
  int kq = lane >> 4;
  int aoff[8], boff[4];
#pragma unroll
  for (int mi = 0; mi < 8; ++mi) {
    int r = (wm << 7) + (mi << 4) + (lane & 15);
    aoff[mi] = r * 64 + ((kq ^ (r & 3)) << 4);
  }
#pragma unroll
  for (int ni = 0; ni < 4; ++ni) {
    int c = (wn << 6) + (ni << 4) + (lane & 15);
    boff[ni] = 16384 + c * 64 + ((kq ^ (c & 3)) << 4);
  }

  f32x4 acc[8][4] = {};

  stage(0, 0);
  stage(1, 1);
#pragma unroll 1
  for (int t = 0; t < NK; ++t) {
    if (t >= NK - 2) asm volatile("s_waitcnt vmcnt(0)" ::: "memory");
    else             asm volatile("s_waitcnt vmcnt(4)" ::: "memory");
    __builtin_amdgcn_s_barrier();
    if (t + 2 < NK) stage(t + 2, (t + 2) & 3);
    const char* base = smem + (t & 3) * 32768;
    bf16x8 av[8], bv[4];
#pragma unroll
    for (int mi = 0; mi < 8; ++mi) av[mi] = *(const bf16x8*)(base + aoff[mi]);
#pragma unroll
    for (int ni = 0; ni < 4; ++ni) bv[ni] = *(const bf16x8*)(base + boff[ni]);
    __builtin_amdgcn_s_setprio(1);
#pragma unroll
    for (int mi = 0; mi < 8; ++mi)
#pragma unroll
      for (int ni = 0; ni < 4; ++ni)
        acc[mi][ni] = __builtin_amdgcn_mfma_f32_16x16x32_bf16(av[mi], bv[ni], acc[mi][ni], 0, 0, 0);
    __builtin_amdgcn_s_setprio(0);
  }

  // ---------- epilogue: acc -> LDS [256 rows][512B] swizzled -> coalesced 16B stores
  __syncthreads();
  const float* biasE = bias + (size_t)e * NFULL;
  u16* OutS = Out + (size_t)split * pstride;
#pragma unroll
  for (int mi = 0; mi < 8; ++mi) {
#pragma unroll
    for (int j = 0; j < 4; ++j) {
      int r = (wm << 7) + (mi << 4) + ((lane >> 4) << 2) + j;
      int m = posStart + r;
      int mc = m < segEnd ? m : segEnd - 1;
      float w = 1.0f;
      if constexpr (SCALE) w = row_w[mc];
#pragma unroll
      for (int ni = 0; ni < 4; ++ni) {
        int c = (wn << 6) + (ni << 4) + (lane & 15);
        float v = acc[mi][ni][j];
        if (split == 0) v += biasE[nt * 256 + c];
        if constexpr (GELU) v = gelu_tanh(v);
        if constexpr (SCALE) v *= w;
        *(u16*)(smem + r * 512 + ((c * 2) ^ ((r & 7) << 4))) = f2bf(v);
      }
    }
  }
  __syncthreads();
  // 512B per row = 32 x 16B chunks; 32 threads/row, 16 rows/pass, 16 passes.
#pragma unroll
  for (int pass = 0; pass < 16; ++pass) {
    int rr = pass * 16 + (tid >> 5);
    int q  = tid & 31;
    int m = posStart + rr;
    if (m < segEnd) {
      uint4 v = *(const uint4*)(smem + rr * 512 + ((q * 16) ^ ((rr & 7) << 4)));
      *((uint4*)(OutS + (size_t)m * NFULL + nt * 256) + q) = v;
    }
  }
}

// ---------- combine: out[tok] = sum over splits x {pos0,pos1} of bf16 partials
__global__ void k_combine(const u16* __restrict__ P, size_t pstride,
                          const int* __restrict__ pos_of, float* __restrict__ out, int Ntok) {
  int tok = (blockIdx.x << 2) + (threadIdx.x >> 6);
  int lane = threadIdx.x & 63;
  if (tok >= Ntok) return;
  int p0 = pos_of[tok * 2], p1 = pos_of[tok * 2 + 1];
  float s[8] = {};
#pragma unroll
  for (int sp = 0; sp < 4; ++sp) {
    bf16x8 a = ((const bf16x8*)(P + sp * pstride + (size_t)p0 * DM))[lane];
    bf16x8 b = ((const bf16x8*)(P + sp * pstride + (size_t)p1 * DM))[lane];
#pragma unroll
    for (int i = 0; i < 8; ++i) s[i] += (float)a[i] + (float)b[i];
  }
  float4* o = (float4*)(out + (size_t)tok * DM + lane * 8);
  o[0] = make_float4(s[0], s[1], s[2], s[3]);
  o[1] = make_float4(s[4], s[5], s[6], s[7]);
}

extern "C" void kernel_launch(void* const* d_in, const int* in_sizes, int n_in,
                              void* d_out, int out_size, void* d_ws, size_t ws_size,
                              hipStream_t stream) {
  const float* x  = (const float*)d_in[0];
  const float* Wr = (const float*)d_in[1];
  const float* br = (const float*)d_in[2];
  const float* W1 = (const float*)d_in[3];
  const float* b1 = (const float*)d_in[4];
  const float* W2 = (const float*)d_in[5];
  const float* b2 = (const float*)d_in[6];
  float* out = (float*)d_out;

  int Ntok = in_sizes[0] / DM;          // 4096
  int npairs = Ntok * 2;                // 8192
  int maxmt = npairs / 256 + NEXP;      // 40
  size_t pstride = (size_t)npairs * DM; // u16 elems per split

  char* p = (char*)d_ws;
  u16* W1T = (u16*)p;  p += (size_t)NEXP * DFF * DM * 2;
  u16* W2T = (u16*)p;  p += (size_t)NEXP * DM * DFF * 2;
  u16* Xg  = (u16*)p;  p += (size_t)npairs * DM * 2;
  u16* H   = (u16*)p;  p += (size_t)npairs * DFF * 2;
  u16* Part = (u16*)p; p += 4 * pstride * 2;          // [4][npairs][DM] bf16
  int* sel_idx   = (int*)p;   p += (size_t)npairs * 4;
  float* sel_w   = (float*)p; p += (size_t)npairs * 4;
  int* pos_of    = (int*)p;   p += (size_t)npairs * 4;
  int* row_token = (int*)p;   p += (size_t)npairs * 4;
  float* row_w   = (float*)p; p += (size_t)npairs * 4;
  int* tileMeta  = (int*)p;   p += (size_t)(maxmt * 3 + 16) * 4;
  int* gMeta     = (int*)p;   p += 64;

  k_prep<<<dim3(4096 + Ntok / 4), 256, 0, stream>>>(W1, W1T, W2, W2T, x, Wr, br,
                                                    sel_idx, sel_w, Ntok);
  k_scatter<<<dim3(1), 1024, 0, stream>>>(sel_idx, sel_w, npairs, row_token, row_w,
                                          pos_of, tileMeta, gMeta);
  k_gather<<<dim3(npairs / 4), 256, 0, stream>>>(x, row_token, Xg, npairs);
  // GEMM1: H = gelu(Xg * W1T + b1), no split
  k_gemm256<DFF, DM, 1, true, false>
      <<<dim3(maxmt * (DFF / 256)), 512, 0, stream>>>(
          Xg, W1T, b1, nullptr, H, 0, tileMeta, gMeta, maxmt);
  // GEMM2: Part[s] = (H_s * W2T_s + (s==0)*b2) * row_w, split-K=4
  k_gemm256<DM, DFF, 4, false, true>
      <<<dim3(maxmt * (DM / 256) * 4), 512, 0, stream>>>(
          H, W2T, b2, row_w, Part, pstride, tileMeta, gMeta, maxmt);
  k_combine<<<dim3(Ntok / 4), 256, 0, stream>>>(Part, pstride, pos_of, out, Ntok);
}

// Round 7
// 183.718 us; speedup vs baseline: 1.3641x; 1.0429x over previous
//
#include <hip/hip_runtime.h>
#include <hip/hip_bf16.h>
#include <cstdint>

typedef unsigned short u16;
typedef __bf16 bf16_t;
typedef __bf16 bf16x8 __attribute__((ext_vector_type(8)));
typedef float f32x4 __attribute__((ext_vector_type(4)));

#define DM   512
#define DFF  2048
#define NEXP 8

__device__ __forceinline__ u16 f2bf(float f) {
  bf16_t b = (bf16_t)f;
  return __builtin_bit_cast(u16, b);
}
__device__ __forceinline__ uint32_t pack_bf2(float lo, float hi) {
  return (uint32_t)f2bf(lo) | ((uint32_t)f2bf(hi) << 16);
}
__device__ __forceinline__ float gelu_tanh(float x) {
  float x3 = x * x * x;
  float z = 0.7978845608028654f * (x + 0.044715f * x3);
  float az = fabsf(z);
  float e = __expf(2.0f * az);
  float t = 1.0f - 2.0f / (e + 1.0f);
  t = copysignf(t, z);
  return 0.5f * x * (1.0f + t);
}
__device__ __forceinline__ void async16(const u16* g, u16* l) {
  __builtin_amdgcn_global_load_lds((const __attribute__((address_space(1))) void*)g,
                                   (__attribute__((address_space(3))) void*)l, 16, 0, 0);
}

// ---------- transpose tile body: src [R][C] f32 (+e offset) -> dst [C][R] bf16
__device__ __forceinline__ void transpose_tile(const float* __restrict__ s,
                                               u16* __restrict__ d, int R, int C,
                                               int tileIdx) {
  __shared__ u16 tile[64][66];
  int tilesC = C >> 6;
  int bR = (tileIdx / tilesC) << 6;
  int bC = (tileIdx % tilesC) << 6;
  int rr = threadIdx.x >> 4;
  int cc = (threadIdx.x & 15) << 2;
#pragma unroll
  for (int i = 0; i < 4; ++i) {
    int r = (i << 4) + rr;
    float4 v = *(const float4*)(s + (size_t)(bR + r) * C + bC + cc);
    *(uint32_t*)&tile[r][cc]     = pack_bf2(v.x, v.y);
    *(uint32_t*)&tile[r][cc + 2] = pack_bf2(v.z, v.w);
  }
  __syncthreads();
  int c0 = threadIdx.x >> 5;
  int j  = (threadIdx.x & 31) << 1;
#pragma unroll
  for (int i = 0; i < 8; ++i) {
    int c = (i << 3) + c0;
    uint32_t v = (uint32_t)tile[j][c] | ((uint32_t)tile[j + 1][c] << 16);
    *(uint32_t*)(&d[(size_t)(bC + c) * R + bR + j]) = v;
  }
}

// ---------- fused prep: W1 transpose | W2 transpose | router
__global__ void k_prep(const float* __restrict__ W1, u16* __restrict__ W1T,
                       const float* __restrict__ W2, u16* __restrict__ W2T,
                       const float* __restrict__ x, const float* __restrict__ Wr,
                       const float* __restrict__ br, int* __restrict__ sel_idx,
                       float* __restrict__ sel_w, int Ntok) {
  int b = blockIdx.x;
  if (b < 2048) {
    int e = b >> 8, t = b & 255;
    transpose_tile(W1 + (size_t)e * DM * DFF, W1T + (size_t)e * DM * DFF, DM, DFF, t);
    return;
  }
  if (b < 4096) {
    int e = (b - 2048) >> 8, t = (b - 2048) & 255;
    transpose_tile(W2 + (size_t)e * DFF * DM, W2T + (size_t)e * DFF * DM, DFF, DM, t);
    return;
  }
  int rb = b - 4096;
  int wid = threadIdx.x >> 6;
  int lane = threadIdx.x & 63;
  int tok = (rb << 2) + wid;
  if (tok >= Ntok) return;
  const float4* xr = (const float4*)(x + (size_t)tok * DM);
  float4 x0 = xr[lane * 2], x1 = xr[lane * 2 + 1];
  float logit[NEXP];
#pragma unroll
  for (int e = 0; e < NEXP; ++e) {
    const float4* wr = (const float4*)(Wr + e * DM);
    float4 w0 = wr[lane * 2], w1 = wr[lane * 2 + 1];
    float p = x0.x * w0.x + x0.y * w0.y + x0.z * w0.z + x0.w * w0.w
            + x1.x * w1.x + x1.y * w1.y + x1.z * w1.z + x1.w * w1.w;
#pragma unroll
    for (int off = 32; off; off >>= 1) p += __shfl_xor(p, off, 64);
    logit[e] = p + br[e];
  }
  if (lane == 0) {
    float mx = logit[0];
#pragma unroll
    for (int e = 1; e < NEXP; ++e) mx = fmaxf(mx, logit[e]);
    float pr[NEXP];
#pragma unroll
    for (int e = 0; e < NEXP; ++e) pr[e] = __expf(logit[e] - mx);
    int i0 = 0;
#pragma unroll
    for (int e = 1; e < NEXP; ++e) if (pr[e] > pr[i0]) i0 = e;
    int i1 = -1;
#pragma unroll
    for (int e = 0; e < NEXP; ++e) {
      if (e == i0) continue;
      if (i1 < 0 || pr[e] > pr[i1]) i1 = e;
    }
    float s2 = pr[i0] + pr[i1];
    sel_idx[tok * 2]     = i0;
    sel_idx[tok * 2 + 1] = i1;
    sel_w[tok * 2]       = pr[i0] / s2;
    sel_w[tok * 2 + 1]   = pr[i1] / s2;
  }
}

// ---------- scatter (1 block, ballot-based), 256-row tile granularity
__global__ void k_scatter(const int* __restrict__ sel_idx, const float* __restrict__ sel_w,
                          int npairs, int* __restrict__ row_token, float* __restrict__ row_w,
                          int* __restrict__ pos_of, int* __restrict__ tileMeta,
                          int* __restrict__ gMeta) {
  __shared__ int cnt[NEXP], offs[NEXP], cur[NEXP];
  int tid = threadIdx.x;
  int lane = tid & 63;
  if (tid < NEXP) { cnt[tid] = 0; cur[tid] = 0; }
  __syncthreads();
  for (int p = tid; p < npairs; p += blockDim.x) {
    int e = sel_idx[p];
#pragma unroll
    for (int ex = 0; ex < NEXP; ++ex) {
      unsigned long long m = __ballot(e == ex);
      if (lane == 0 && m) atomicAdd(&cnt[ex], __popcll(m));
    }
  }
  __syncthreads();
  if (tid == 0) {
    int o = 0, nmt = 0;
    for (int e = 0; e < NEXP; ++e) {
      offs[e] = o;
      int c = cnt[e];
      int nt = (c + 255) >> 8;
      for (int t = 0; t < nt; ++t) {
        tileMeta[nmt * 3 + 0] = o + t * 256;
        tileMeta[nmt * 3 + 1] = o + c;
        tileMeta[nmt * 3 + 2] = e;
        ++nmt;
      }
      o += c;
    }
    gMeta[0] = nmt;
  }
  __syncthreads();
  for (int p = tid; p < npairs; p += blockDim.x) {
    int e = sel_idx[p];
    int pos = 0;
#pragma unroll
    for (int ex = 0; ex < NEXP; ++ex) {
      unsigned long long m = __ballot(e == ex);
      if (m) {
        int leader = __ffsll((long long)m) - 1;
        int base = 0;
        if (lane == leader) base = atomicAdd(&cur[ex], __popcll(m));
        base = __shfl(base, leader, 64);
        if (e == ex)
          pos = offs[ex] + base + __popcll(m & ((1ull << lane) - 1ull));
      }
    }
    row_token[pos] = p >> 1;
    row_w[pos] = sel_w[p];
    pos_of[p] = pos;
  }
}

// ---------- gather selected token rows -> bf16
__global__ void k_gather(const float* __restrict__ x, const int* __restrict__ row_token,
                         u16* __restrict__ Xg, int npairs) {
  int pos = (blockIdx.x << 2) + (threadIdx.x >> 6);
  int lane = threadIdx.x & 63;
  if (pos >= npairs) return;
  int tok = row_token[pos];
  const float4* src = (const float4*)(x + (size_t)tok * DM);
  float4 a = src[lane * 2], b = src[lane * 2 + 1];
  uint4 o;
  o.x = pack_bf2(a.x, a.y);
  o.y = pack_bf2(a.z, a.w);
  o.z = pack_bf2(b.x, b.y);
  o.w = pack_bf2(b.z, b.w);
  ((uint4*)(Xg + (size_t)pos * DM))[lane] = o;
}

// ---------- 256x256 grouped GEMM, 512 thr / 8 waves (2Mx4N), BK=32,
// 4-slot LDS ring, stage-lead-2, counted vmcnt, register-double-buffered
// fragments: ds_read(tile t+1) issued before MFMA(tile t) -> LDS || MFMA overlap.
template <int NFULL, int KTOT, int NSPLIT, bool GELU, bool SCALE>
__launch_bounds__(512, 2)
__global__ void k_gemm256(const u16* __restrict__ A, const u16* __restrict__ BT,
                          const float* __restrict__ bias, const float* __restrict__ row_w,
                          u16* __restrict__ Out, size_t pstride,
                          const int* __restrict__ tileMeta, const int* __restrict__ gMeta,
                          int maxmt) {
  constexpr int NTN = NFULL / 256;
  constexpr int KCH = KTOT / NSPLIT;
  constexpr int NK  = KCH / 32;
  static_assert(NK % 2 == 0 && NK >= 4, "NK even");

  __shared__ __align__(16) char smem[131072];  // slot s: A at s*32768 (16KB), B at +16384

  int NB = gridDim.x;
  int bid = blockIdx.x;
  int wg = ((NB & 7) == 0) ? ((bid & 7) * (NB >> 3) + (bid >> 3)) : bid;  // XCD chunking
  int nt = wg % NTN;
  int rem = wg / NTN;
  int mt = rem % maxmt;
  int split = rem / maxmt;
  if (mt >= gMeta[0]) return;
  int posStart = tileMeta[mt * 3 + 0];
  int segEnd   = tileMeta[mt * 3 + 1];
  int e        = tileMeta[mt * 3 + 2];

  int tid = threadIdx.x, lane = tid & 63, wid = tid >> 6;
  int wm = wid >> 2, wn = wid & 3;   // 2 x 4 waves; wave tile 128 x 64

  const u16* Ab = A + (size_t)split * KCH;
  const u16* Bb = BT + ((size_t)e * NFULL + (size_t)nt * 256) * KTOT + (size_t)split * KCH;

  // staging: LDS row trow (64B), chunk tc; source pre-swizzled chunk = tc ^ ((row>>1)&3)
  // (2-way max on fragment read = free per m136). f(row+16)=f(row), f(row+128)=f(row).
  int trow = tid >> 2, tc = tid & 3;
  const u16 *aP0, *aP1, *bP0, *bP1;
  {
    int fr = (trow >> 1) & 3;
    int r1 = 128 + trow;
    int g0 = posStart + trow; if (g0 >= segEnd) g0 = segEnd - 1;
    int g1 = posStart + r1;   if (g1 >= segEnd) g1 = segEnd - 1;
    aP0 = Ab + (size_t)g0 * KTOT + ((tc ^ fr) << 3);
    aP1 = Ab + (size_t)g1 * KTOT + ((tc ^ fr) << 3);
    bP0 = Bb + (size_t)trow * KTOT + ((tc ^ fr) << 3);
    bP1 = Bb + (size_t)r1 * KTOT + ((tc ^ fr) << 3);
  }

  auto stage = [&](int t, int slot) {
    char* dst = smem + slot * 32768;
    async16(aP0 + t * 32, (u16*)(dst + tid * 16));
    async16(aP1 + t * 32, (u16*)(dst + 8192 + tid * 16));
    async16(bP0 + t * 32, (u16*)(dst + 16384 + tid * 16));
    async16(bP1 + t * 32, (u16*)(dst + 24576 + tid * 16));
  };

  // fragment base byte offsets (mi/ni strides of 1024 fold into ds_read immediates)
  int kq = lane >> 4;
  int r0 = (wm << 7) + (lane & 15);
  int c0 = (wn << 6) + (lane & 15);
  int aoff0 = r0 * 64 + ((kq ^ ((r0 >> 1) & 3)) << 4);
  int boff0 = 16384 + c0 * 64 + ((kq ^ ((c0 >> 1) & 3)) << 4);

  bf16x8 av0[8], bv0[4], av1[8], bv1[4];
  f32x4 acc[8][4] = {};

#define LOADFRAGS(av, bv, slotbase)                                        \
  {                                                                        \
    const char* _b = (slotbase);                                           \
    _Pragma("unroll") for (int i = 0; i < 8; ++i)                          \
        av[i] = *(const bf16x8*)(_b + aoff0 + i * 1024);                   \
    _Pragma("unroll") for (int i = 0; i < 4; ++i)                          \
        bv[i] = *(const bf16x8*)(_b + boff0 + i * 1024);                   \
  }

#define MFMACL(av, bv)                                                     \
  __builtin_amdgcn_s_setprio(1);                                           \
  _Pragma("unroll") for (int mi = 0; mi < 8; ++mi)                         \
    _Pragma("unroll") for (int ni = 0; ni < 4; ++ni)                       \
      acc[mi][ni] = __builtin_amdgcn_mfma_f32_16x16x32_bf16(               \
          av[mi], bv[ni], acc[mi][ni], 0, 0, 0);                           \
  __builtin_amdgcn_s_setprio(0);

  stage(0, 0);
  stage(1, 1);
  asm volatile("s_waitcnt vmcnt(4)" ::: "memory");   // tile 0 landed
  __builtin_amdgcn_s_barrier();
  LOADFRAGS(av0, bv0, smem);                         // tile 0 frags

#pragma unroll 1
  for (int t = 0; t < NK; t += 2) {
    // ---- half-iter A: compute tile t (av0), preload tile t+1 (av1)
    if (t + 2 < NK) {
      stage(t + 2, (t + 2) & 3);
      asm volatile("s_waitcnt vmcnt(4)" ::: "memory");   // tile t+1 landed
    } else {
      asm volatile("s_waitcnt vmcnt(0)" ::: "memory");
    }
    __builtin_amdgcn_s_barrier();
    LOADFRAGS(av1, bv1, smem + ((t + 1) & 3) * 32768);   // 12 reads in flight...
    MFMACL(av0, bv0);                                    // ...overlap these MFMAs
    // ---- half-iter B: compute tile t+1 (av1), preload tile t+2 (av0)
    if (t + 3 < NK) {
      stage(t + 3, (t + 3) & 3);
      asm volatile("s_waitcnt vmcnt(4)" ::: "memory");
      __builtin_amdgcn_s_barrier();
      LOADFRAGS(av0, bv0, smem + ((t + 2) & 3) * 32768);
    } else if (t + 2 < NK) {
      asm volatile("s_waitcnt vmcnt(0)" ::: "memory");
      __builtin_amdgcn_s_barrier();
      LOADFRAGS(av0, bv0, smem + ((t + 2) & 3) * 32768);
    }
    MFMACL(av1, bv1);
  }
#undef LOADFRAGS
#undef MFMACL

  // ---------- epilogue: acc -> LDS [256 rows][512B] swizzled -> coalesced 16B stores
  __syncthreads();
  const float* biasE = bias + (size_t)e * NFULL;
  u16* OutS = Out + (size_t)split * pstride;
#pragma unroll
  for (int mi = 0; mi < 8; ++mi) {
#pragma unroll
    for (int j = 0; j < 4; ++j) {
      int r = (wm << 7) + (mi << 4) + ((lane >> 4) << 2) + j;
      int m = posStart + r;
      int mc = m < segEnd ? m : segEnd - 1;
      float w = 1.0f;
      if constexpr (SCALE) w = row_w[mc];
#pragma unroll
      for (int ni = 0; ni < 4; ++ni) {
        int c = (wn << 6) + (ni << 4) + (lane & 15);
        float v = acc[mi][ni][j];
        if (split == 0) v += biasE[nt * 256 + c];
        if constexpr (GELU) v = gelu_tanh(v);
        if constexpr (SCALE) v *= w;
        *(u16*)(smem + r * 512 + ((c * 2) ^ ((r & 7) << 4))) = f2bf(v);
      }
    }
  }
  __syncthreads();
  // 512B per row = 32 x 16B chunks; 32 threads/row, 16 rows/pass, 16 passes.
#pragma unroll
  for (int pass = 0; pass < 16; ++pass) {
    int rr = pass * 16 + (tid >> 5);
    int q  = tid & 31;
    int m = posStart + rr;
    if (m < segEnd) {
      uint4 v = *(const uint4*)(smem + rr * 512 + ((q * 16) ^ ((rr & 7) << 4)));
      *((uint4*)(OutS + (size_t)m * NFULL + nt * 256) + q) = v;
    }
  }
}

// ---------- combine: out[tok] = sum over splits x {pos0,pos1} of bf16 partials
__global__ void k_combine(const u16* __restrict__ P, size_t pstride,
                          const int* __restrict__ pos_of, float* __restrict__ out, int Ntok) {
  int tok = (blockIdx.x << 2) + (threadIdx.x >> 6);
  int lane = threadIdx.x & 63;
  if (tok >= Ntok) return;
  int p0 = pos_of[tok * 2], p1 = pos_of[tok * 2 + 1];
  float s[8] = {};
#pragma unroll
  for (int sp = 0; sp < 4; ++sp) {
    bf16x8 a = ((const bf16x8*)(P + sp * pstride + (size_t)p0 * DM))[lane];
    bf16x8 b = ((const bf16x8*)(P + sp * pstride + (size_t)p1 * DM))[lane];
#pragma unroll
    for (int i = 0; i < 8; ++i) s[i] += (float)a[i] + (float)b[i];
  }
  float4* o = (float4*)(out + (size_t)tok * DM + lane * 8);
  o[0] = make_float4(s[0], s[1], s[2], s[3]);
  o[1] = make_float4(s[4], s[5], s[6], s[7]);
}

extern "C" void kernel_launch(void* const* d_in, const int* in_sizes, int n_in,
                              void* d_out, int out_size, void* d_ws, size_t ws_size,
                              hipStream_t stream) {
  const float* x  = (const float*)d_in[0];
  const float* Wr = (const float*)d_in[1];
  const float* br = (const float*)d_in[2];
  const float* W1 = (const float*)d_in[3];
  const float* b1 = (const float*)d_in[4];
  const float* W2 = (const float*)d_in[5];
  const float* b2 = (const float*)d_in[6];
  float* out = (float*)d_out;

  int Ntok = in_sizes[0] / DM;          // 4096
  int npairs = Ntok * 2;                // 8192
  int maxmt = npairs / 256 + NEXP;      // 40
  size_t pstride = (size_t)npairs * DM; // u16 elems per split

  char* p = (char*)d_ws;
  u16* W1T = (u16*)p;  p += (size_t)NEXP * DFF * DM * 2;
  u16* W2T = (u16*)p;  p += (size_t)NEXP * DM * DFF * 2;
  u16* Xg  = (u16*)p;  p += (size_t)npairs * DM * 2;
  u16* H   = (u16*)p;  p += (size_t)npairs * DFF * 2;
  u16* Part = (u16*)p; p += 4 * pstride * 2;          // [4][npairs][DM] bf16
  int* sel_idx   = (int*)p;   p += (size_t)npairs * 4;
  float* sel_w   = (float*)p; p += (size_t)npairs * 4;
  int* pos_of    = (int*)p;   p += (size_t)npairs * 4;
  int* row_token = (int*)p;   p += (size_t)npairs * 4;
  float* row_w   = (float*)p; p += (size_t)npairs * 4;
  int* tileMeta  = (int*)p;   p += (size_t)(maxmt * 3 + 16) * 4;
  int* gMeta     = (int*)p;   p += 64;

  k_prep<<<dim3(4096 + Ntok / 4), 256, 0, stream>>>(W1, W1T, W2, W2T, x, Wr, br,
                                                    sel_idx, sel_w, Ntok);
  k_scatter<<<dim3(1), 1024, 0, stream>>>(sel_idx, sel_w, npairs, row_token, row_w,
                                          pos_of, tileMeta, gMeta);
  k_gather<<<dim3(npairs / 4), 256, 0, stream>>>(x, row_token, Xg, npairs);
  // GEMM1: H = gelu(Xg * W1T + b1), no split
  k_gemm256<DFF, DM, 1, true, false>
      <<<dim3(maxmt * (DFF / 256)), 512, 0, stream>>>(
          Xg, W1T, b1, nullptr, H, 0, tileMeta, gMeta, maxmt);
  // GEMM2: Part[s] = (H_s * W2T_s + (s==0)*b2) * row_w, split-K=4
  k_gemm256<DM, DFF, 4, false, true>
      <<<dim3(maxmt * (DM / 256) * 4), 512, 0, stream>>>(
          H, W2T, b2, row_w, Part, pstride, tileMeta, gMeta, maxmt);
  k_combine<<<dim3(Ntok / 4), 256, 0, stream>>>(Part, pstride, pos_of, out, Ntok);
}

// Round 8
// 177.363 us; speedup vs baseline: 1.4130x; 1.0358x over previous
//
#include <hip/hip_runtime.h>
#include <hip/hip_bf16.h>
#include <cstdint>

typedef unsigned short u16;
typedef __bf16 bf16_t;
typedef __bf16 bf16x8 __attribute__((ext_vector_type(8)));
typedef float f32x4 __attribute__((ext_vector_type(4)));

#define DM   512
#define DFF  2048
#define NEXP 8

__device__ __forceinline__ u16 f2bf(float f) {
  bf16_t b = (bf16_t)f;
  return __builtin_bit_cast(u16, b);
}
__device__ __forceinline__ uint32_t pack_bf2(float lo, float hi) {
  return (uint32_t)f2bf(lo) | ((uint32_t)f2bf(hi) << 16);
}
__device__ __forceinline__ float gelu_tanh(float x) {
  float x3 = x * x * x;
  float z = 0.7978845608028654f * (x + 0.044715f * x3);
  float az = fabsf(z);
  float e = __expf(2.0f * az);
  float t = 1.0f - 2.0f / (e + 1.0f);
  t = copysignf(t, z);
  return 0.5f * x * (1.0f + t);
}
__device__ __forceinline__ void async16(const u16* g, u16* l) {
  __builtin_amdgcn_global_load_lds((const __attribute__((address_space(1))) void*)g,
                                   (__attribute__((address_space(3))) void*)l, 16, 0, 0);
}

// ---------- transpose tile body: src [R][C] f32 (+e offset) -> dst [C][R] bf16
__device__ __forceinline__ void transpose_tile(const float* __restrict__ s,
                                               u16* __restrict__ d, int R, int C,
                                               int tileIdx) {
  __shared__ u16 tile[64][66];
  int tilesC = C >> 6;
  int bR = (tileIdx / tilesC) << 6;
  int bC = (tileIdx % tilesC) << 6;
  int rr = threadIdx.x >> 4;
  int cc = (threadIdx.x & 15) << 2;
#pragma unroll
  for (int i = 0; i < 4; ++i) {
    int r = (i << 4) + rr;
    float4 v = *(const float4*)(s + (size_t)(bR + r) * C + bC + cc);
    *(uint32_t*)&tile[r][cc]     = pack_bf2(v.x, v.y);
    *(uint32_t*)&tile[r][cc + 2] = pack_bf2(v.z, v.w);
  }
  __syncthreads();
  int c0 = threadIdx.x >> 5;
  int j  = (threadIdx.x & 31) << 1;
#pragma unroll
  for (int i = 0; i < 8; ++i) {
    int c = (i << 3) + c0;
    uint32_t v = (uint32_t)tile[j][c] | ((uint32_t)tile[j + 1][c] << 16);
    *(uint32_t*)(&d[(size_t)(bC + c) * R + bR + j]) = v;
  }
}

// ---------- fused prep: W1 transpose | W2 transpose | router
__global__ void k_prep(const float* __restrict__ W1, u16* __restrict__ W1T,
                       const float* __restrict__ W2, u16* __restrict__ W2T,
                       const float* __restrict__ x, const float* __restrict__ Wr,
                       const float* __restrict__ br, int* __restrict__ sel_idx,
                       float* __restrict__ sel_w, int Ntok) {
  int b = blockIdx.x;
  if (b < 2048) {
    int e = b >> 8, t = b & 255;
    transpose_tile(W1 + (size_t)e * DM * DFF, W1T + (size_t)e * DM * DFF, DM, DFF, t);
    return;
  }
  if (b < 4096) {
    int e = (b - 2048) >> 8, t = (b - 2048) & 255;
    transpose_tile(W2 + (size_t)e * DFF * DM, W2T + (size_t)e * DFF * DM, DFF, DM, t);
    return;
  }
  int rb = b - 4096;
  int wid = threadIdx.x >> 6;
  int lane = threadIdx.x & 63;
  int tok = (rb << 2) + wid;
  if (tok >= Ntok) return;
  const float4* xr = (const float4*)(x + (size_t)tok * DM);
  float4 x0 = xr[lane * 2], x1 = xr[lane * 2 + 1];
  float logit[NEXP];
#pragma unroll
  for (int e = 0; e < NEXP; ++e) {
    const float4* wr = (const float4*)(Wr + e * DM);
    float4 w0 = wr[lane * 2], w1 = wr[lane * 2 + 1];
    float p = x0.x * w0.x + x0.y * w0.y + x0.z * w0.z + x0.w * w0.w
            + x1.x * w1.x + x1.y * w1.y + x1.z * w1.z + x1.w * w1.w;
#pragma unroll
    for (int off = 32; off; off >>= 1) p += __shfl_xor(p, off, 64);
    logit[e] = p + br[e];
  }
  if (lane == 0) {
    float mx = logit[0];
#pragma unroll
    for (int e = 1; e < NEXP; ++e) mx = fmaxf(mx, logit[e]);
    float pr[NEXP];
#pragma unroll
    for (int e = 0; e < NEXP; ++e) pr[e] = __expf(logit[e] - mx);
    int i0 = 0;
#pragma unroll
    for (int e = 1; e < NEXP; ++e) if (pr[e] > pr[i0]) i0 = e;
    int i1 = -1;
#pragma unroll
    for (int e = 0; e < NEXP; ++e) {
      if (e == i0) continue;
      if (i1 < 0 || pr[e] > pr[i1]) i1 = e;
    }
    float s2 = pr[i0] + pr[i1];
    sel_idx[tok * 2]     = i0;
    sel_idx[tok * 2 + 1] = i1;
    sel_w[tok * 2]       = pr[i0] / s2;
    sel_w[tok * 2 + 1]   = pr[i1] / s2;
  }
}

// ---------- scatter (1 block, ballot-based), 256-row tile granularity
__global__ void k_scatter(const int* __restrict__ sel_idx, const float* __restrict__ sel_w,
                          int npairs, int* __restrict__ row_token, float* __restrict__ row_w,
                          int* __restrict__ pos_of, int* __restrict__ tileMeta,
                          int* __restrict__ gMeta) {
  __shared__ int cnt[NEXP], offs[NEXP], cur[NEXP];
  int tid = threadIdx.x;
  int lane = tid & 63;
  if (tid < NEXP) { cnt[tid] = 0; cur[tid] = 0; }
  __syncthreads();
  for (int p = tid; p < npairs; p += blockDim.x) {
    int e = sel_idx[p];
#pragma unroll
    for (int ex = 0; ex < NEXP; ++ex) {
      unsigned long long m = __ballot(e == ex);
      if (lane == 0 && m) atomicAdd(&cnt[ex], __popcll(m));
    }
  }
  __syncthreads();
  if (tid == 0) {
    int o = 0, nmt = 0;
    for (int e = 0; e < NEXP; ++e) {
      offs[e] = o;
      int c = cnt[e];
      int nt = (c + 255) >> 8;
      for (int t = 0; t < nt; ++t) {
        tileMeta[nmt * 3 + 0] = o + t * 256;
        tileMeta[nmt * 3 + 1] = o + c;
        tileMeta[nmt * 3 + 2] = e;
        ++nmt;
      }
      o += c;
    }
    gMeta[0] = nmt;
  }
  __syncthreads();
  for (int p = tid; p < npairs; p += blockDim.x) {
    int e = sel_idx[p];
    int pos = 0;
#pragma unroll
    for (int ex = 0; ex < NEXP; ++ex) {
      unsigned long long m = __ballot(e == ex);
      if (m) {
        int leader = __ffsll((long long)m) - 1;
        int base = 0;
        if (lane == leader) base = atomicAdd(&cur[ex], __popcll(m));
        base = __shfl(base, leader, 64);
        if (e == ex)
          pos = offs[ex] + base + __popcll(m & ((1ull << lane) - 1ull));
      }
    }
    row_token[pos] = p >> 1;
    row_w[pos] = sel_w[p];
    pos_of[p] = pos;
  }
}

// ---------- gather selected token rows -> bf16
__global__ void k_gather(const float* __restrict__ x, const int* __restrict__ row_token,
                         u16* __restrict__ Xg, int npairs) {
  int pos = (blockIdx.x << 2) + (threadIdx.x >> 6);
  int lane = threadIdx.x & 63;
  if (pos >= npairs) return;
  int tok = row_token[pos];
  const float4* src = (const float4*)(x + (size_t)tok * DM);
  float4 a = src[lane * 2], b = src[lane * 2 + 1];
  uint4 o;
  o.x = pack_bf2(a.x, a.y);
  o.y = pack_bf2(a.z, a.w);
  o.z = pack_bf2(b.x, b.y);
  o.w = pack_bf2(b.z, b.w);
  ((uint4*)(Xg + (size_t)pos * DM))[lane] = o;
}

// ---------- 256x128 grouped GEMM, 256 thr / 4 waves (2Mx2N), BK=32,
// 3-slot LDS ring (72KB -> 2 blocks/CU), stage-lead-2, counted vmcnt(6),
// two fine phases per K-tile: {reads; stage; bar; lgk0; prio; 16 MFMA; bar}.
template <int NFULL, int KTOT, int NSPLIT, bool GELU, bool SCALE>
__launch_bounds__(256, 2)
__global__ void k_gemm(const u16* __restrict__ A, const u16* __restrict__ BT,
                       const float* __restrict__ bias, const float* __restrict__ row_w,
                       u16* __restrict__ Out, size_t pstride,
                       const int* __restrict__ tileMeta, const int* __restrict__ gMeta,
                       int maxmt) {
  constexpr int NTN = NFULL / 128;
  constexpr int KCH = KTOT / NSPLIT;
  constexpr int NK  = KCH / 32;
  constexpr int SLOT = 24576;   // A [256][32]u16 16KB @0, B [128][32]u16 8KB @16384

  __shared__ __align__(16) char smem[3 * SLOT];   // 72KB; epilogue reuses 64KB

  int NB = gridDim.x;
  int bid = blockIdx.x;
  int wg = ((NB & 7) == 0) ? ((bid & 7) * (NB >> 3) + (bid >> 3)) : bid;  // XCD chunking
  int nt = wg % NTN;
  int rem = wg / NTN;
  int mt = rem % maxmt;
  int split = rem / maxmt;
  if (mt >= gMeta[0]) return;
  int posStart = tileMeta[mt * 3 + 0];
  int segEnd   = tileMeta[mt * 3 + 1];
  int e        = tileMeta[mt * 3 + 2];

  int tid = threadIdx.x, lane = tid & 63, wid = tid >> 6;
  int wm = wid >> 1, wn = wid & 1;   // 2 x 2 waves; wave tile 128 x 64

  const u16* Ab = A + (size_t)split * KCH;
  const u16* Bb = BT + ((size_t)e * NFULL + (size_t)nt * 128) * KTOT + (size_t)split * KCH;

  // staging: instr covers 64 rows (64B each); src pre-swizzled chunk = tc ^ ((r>>1)&3)
  int trow = tid >> 2, tc = tid & 3;
  const u16* aS[4];
  const u16* bS[2];
#pragma unroll
  for (int i = 0; i < 4; ++i) {
    int r = i * 64 + trow;
    int g = posStart + r; if (g >= segEnd) g = segEnd - 1;
    aS[i] = Ab + (size_t)g * KTOT + (size_t)((tc ^ ((r >> 1) & 3)) << 3);
  }
#pragma unroll
  for (int j = 0; j < 2; ++j) {
    int r = j * 64 + trow;
    bS[j] = Bb + (size_t)r * KTOT + (size_t)((tc ^ ((r >> 1) & 3)) << 3);
  }

  // stage halves: h=0 -> A instrs 0..2 ; h=1 -> A instr 3 + B instrs 0..1  (3 each)
  auto stageH = [&](int kt, int h) {
    char* dst = smem + (kt % 3) * SLOT;
    if (h == 0) {
#pragma unroll
      for (int i = 0; i < 3; ++i)
        async16(aS[i] + kt * 32, (u16*)(dst + i * 4096 + tid * 16));
    } else {
      async16(aS[3] + kt * 32, (u16*)(dst + 3 * 4096 + tid * 16));
#pragma unroll
      for (int j = 0; j < 2; ++j)
        async16(bS[j] + kt * 32, (u16*)(dst + 16384 + j * 4096 + tid * 16));
    }
  };

  // fragment byte offsets
  int l15 = lane & 15, g4 = lane >> 4;
  int aBase = ((wm << 7) + l15) * 64 + ((g4 ^ ((l15 >> 1) & 3)) << 4);
  int bBase = 16384 + ((wn << 6) + l15) * 64 + ((g4 ^ ((l15 >> 1) & 3)) << 4);

  f32x4 acc[8][4] = {};
  bf16x8 av[4], bv[4];

  stageH(0, 0); stageH(0, 1);
  stageH(1, 0); stageH(1, 1);
  asm volatile("s_waitcnt vmcnt(6)" ::: "memory");   // tile 0 landed
  __builtin_amdgcn_s_barrier();
  asm volatile("" ::: "memory");

#pragma unroll 1
  for (int kt = 0; kt < NK; ++kt) {
    const char* base = smem + (kt % 3) * SLOT;
    // ---- phase 0: read bv[0..3] + av[mi 0..3]; stage half0 of kt+2; MFMA mh=0
#pragma unroll
    for (int ni = 0; ni < 4; ++ni) bv[ni] = *(const bf16x8*)(base + bBase + ni * 1024);
#pragma unroll
    for (int mi = 0; mi < 4; ++mi) av[mi] = *(const bf16x8*)(base + aBase + mi * 1024);
    if (kt + 2 < NK) stageH(kt + 2, 0);
    __builtin_amdgcn_s_barrier();
    asm volatile("s_waitcnt lgkmcnt(0)" ::: "memory");
    __builtin_amdgcn_s_setprio(1);
#pragma unroll
    for (int mi = 0; mi < 4; ++mi)
#pragma unroll
      for (int ni = 0; ni < 4; ++ni)
        acc[mi][ni] = __builtin_amdgcn_mfma_f32_16x16x32_bf16(av[mi], bv[ni], acc[mi][ni], 0, 0, 0);
    __builtin_amdgcn_s_setprio(0);
    __builtin_amdgcn_s_barrier();
    asm volatile("" ::: "memory");
    // ---- phase 1: read av[mi 4..7]; stage half1 of kt+2; vmcnt for kt+1; MFMA mh=1
#pragma unroll
    for (int mi = 0; mi < 4; ++mi) av[mi] = *(const bf16x8*)(base + aBase + 4096 + mi * 1024);
    if (kt + 2 < NK) stageH(kt + 2, 1);
    if (kt + 1 < NK) {
      if (kt + 2 < NK) asm volatile("s_waitcnt vmcnt(6)" ::: "memory");
      else             asm volatile("s_waitcnt vmcnt(0)" ::: "memory");
    }
    __builtin_amdgcn_s_barrier();
    asm volatile("s_waitcnt lgkmcnt(0)" ::: "memory");
    __builtin_amdgcn_s_setprio(1);
#pragma unroll
    for (int mi = 0; mi < 4; ++mi)
#pragma unroll
      for (int ni = 0; ni < 4; ++ni)
        acc[4 + mi][ni] = __builtin_amdgcn_mfma_f32_16x16x32_bf16(av[mi], bv[ni], acc[4 + mi][ni], 0, 0, 0);
    __builtin_amdgcn_s_setprio(0);
    __builtin_amdgcn_s_barrier();
    asm volatile("" ::: "memory");
  }

  // ---------- epilogue: acc -> LDS [256 rows][256B] swizzled -> coalesced 16B stores
  __syncthreads();
  const float* biasE = bias + (size_t)e * NFULL;
  u16* OutS = Out + (size_t)split * pstride;
#pragma unroll
  for (int mi = 0; mi < 8; ++mi) {
#pragma unroll
    for (int j = 0; j < 4; ++j) {
      int r = (wm << 7) + (mi << 4) + ((lane >> 4) << 2) + j;
      int m = posStart + r;
      int mc = m < segEnd ? m : segEnd - 1;
      float w = 1.0f;
      if constexpr (SCALE) w = row_w[mc];
#pragma unroll
      for (int ni = 0; ni < 4; ++ni) {
        int c = (wn << 6) + (ni << 4) + (lane & 15);
        float v = acc[mi][ni][j];
        if (split == 0) v += biasE[nt * 128 + c];
        if constexpr (GELU) v = gelu_tanh(v);
        if constexpr (SCALE) v *= w;
        *(u16*)(smem + r * 256 + ((c * 2) ^ ((r & 7) << 4))) = f2bf(v);
      }
    }
  }
  __syncthreads();
  // 256B per row = 16 x 16B chunks; 16 threads/row, 16 rows/pass, 16 passes.
#pragma unroll
  for (int pass = 0; pass < 16; ++pass) {
    int rr = pass * 16 + (tid >> 4);
    int q  = tid & 15;
    int m = posStart + rr;
    if (m < segEnd) {
      uint4 v = *(const uint4*)(smem + rr * 256 + ((q * 16) ^ ((rr & 7) << 4)));
      *((uint4*)(OutS + (size_t)m * NFULL + nt * 128) + q) = v;
    }
  }
}

// ---------- combine: out[tok] = sum over splits x {pos0,pos1} of bf16 partials
template <int NSPLIT>
__global__ void k_combine(const u16* __restrict__ P, size_t pstride,
                          const int* __restrict__ pos_of, float* __restrict__ out, int Ntok) {
  int tok = (blockIdx.x << 2) + (threadIdx.x >> 6);
  int lane = threadIdx.x & 63;
  if (tok >= Ntok) return;
  int p0 = pos_of[tok * 2], p1 = pos_of[tok * 2 + 1];
  float s[8] = {};
#pragma unroll
  for (int sp = 0; sp < NSPLIT; ++sp) {
    bf16x8 a = ((const bf16x8*)(P + sp * pstride + (size_t)p0 * DM))[lane];
    bf16x8 b = ((const bf16x8*)(P + sp * pstride + (size_t)p1 * DM))[lane];
#pragma unroll
    for (int i = 0; i < 8; ++i) s[i] += (float)a[i] + (float)b[i];
  }
  float4* o = (float4*)(out + (size_t)tok * DM + lane * 8);
  o[0] = make_float4(s[0], s[1], s[2], s[3]);
  o[1] = make_float4(s[4], s[5], s[6], s[7]);
}

extern "C" void kernel_launch(void* const* d_in, const int* in_sizes, int n_in,
                              void* d_out, int out_size, void* d_ws, size_t ws_size,
                              hipStream_t stream) {
  const float* x  = (const float*)d_in[0];
  const float* Wr = (const float*)d_in[1];
  const float* br = (const float*)d_in[2];
  const float* W1 = (const float*)d_in[3];
  const float* b1 = (const float*)d_in[4];
  const float* W2 = (const float*)d_in[5];
  const float* b2 = (const float*)d_in[6];
  float* out = (float*)d_out;

  int Ntok = in_sizes[0] / DM;          // 4096
  int npairs = Ntok * 2;                // 8192
  int maxmt = npairs / 256 + NEXP;      // 40
  size_t pstride = (size_t)npairs * DM; // u16 elems per split

  char* p = (char*)d_ws;
  u16* W1T = (u16*)p;  p += (size_t)NEXP * DFF * DM * 2;
  u16* W2T = (u16*)p;  p += (size_t)NEXP * DM * DFF * 2;
  u16* Xg  = (u16*)p;  p += (size_t)npairs * DM * 2;
  u16* H   = (u16*)p;  p += (size_t)npairs * DFF * 2;
  u16* Part = (u16*)p; p += 4 * pstride * 2;          // [4][npairs][DM] bf16
  int* sel_idx   = (int*)p;   p += (size_t)npairs * 4;
  float* sel_w   = (float*)p; p += (size_t)npairs * 4;
  int* pos_of    = (int*)p;   p += (size_t)npairs * 4;
  int* row_token = (int*)p;   p += (size_t)npairs * 4;
  float* row_w   = (float*)p; p += (size_t)npairs * 4;
  int* tileMeta  = (int*)p;   p += (size_t)(maxmt * 3 + 16) * 4;
  int* gMeta     = (int*)p;   p += 64;

  k_prep<<<dim3(4096 + Ntok / 4), 256, 0, stream>>>(W1, W1T, W2, W2T, x, Wr, br,
                                                    sel_idx, sel_w, Ntok);
  k_scatter<<<dim3(1), 1024, 0, stream>>>(sel_idx, sel_w, npairs, row_token, row_w,
                                          pos_of, tileMeta, gMeta);
  k_gather<<<dim3(npairs / 4), 256, 0, stream>>>(x, row_token, Xg, npairs);
  // GEMM1: H = gelu(Xg * W1T + b1), BM=256 BN=128, no split  (grid 40*16=640)
  k_gemm<DFF, DM, 1, true, false>
      <<<dim3(maxmt * (DFF / 128)), 256, 0, stream>>>(
          Xg, W1T, b1, nullptr, H, 0, tileMeta, gMeta, maxmt);
  // GEMM2: Part[s] = (H_s * W2T_s + (s==0)*b2) * row_w, split-K=4  (grid 40*4*4=640)
  k_gemm<DM, DFF, 4, false, true>
      <<<dim3(maxmt * (DM / 128) * 4), 256, 0, stream>>>(
          H, W2T, b2, row_w, Part, pstride, tileMeta, gMeta, maxmt);
  k_combine<4><<<dim3(Ntok / 4), 256, 0, stream>>>(Part, pstride, pos_of, out, Ntok);
}

// Round 9
// 143.340 us; speedup vs baseline: 1.7484x; 1.2374x over previous
//
#include <hip/hip_runtime.h>
#include <hip/hip_bf16.h>
#include <cstdint>

typedef unsigned short u16;
typedef __bf16 bf16_t;
typedef __bf16 bf16x8 __attribute__((ext_vector_type(8)));
typedef float f32x4 __attribute__((ext_vector_type(4)));

#define DM   512
#define DFF  2048
#define NEXP 8

__device__ __forceinline__ u16 f2bf(float f) {
  bf16_t b = (bf16_t)f;
  return __builtin_bit_cast(u16, b);
}
__device__ __forceinline__ uint32_t pack_bf2(float lo, float hi) {
  return (uint32_t)f2bf(lo) | ((uint32_t)f2bf(hi) << 16);
}
__device__ __forceinline__ float gelu_tanh(float x) {
  float x3 = x * x * x;
  float z = 0.7978845608028654f * (x + 0.044715f * x3);
  float az = fabsf(z);
  float e = __expf(2.0f * az);
  float t = 1.0f - 2.0f / (e + 1.0f);
  t = copysignf(t, z);
  return 0.5f * x * (1.0f + t);
}
__device__ __forceinline__ void async16(const u16* g, u16* l) {
  __builtin_amdgcn_global_load_lds((const __attribute__((address_space(1))) void*)g,
                                   (__attribute__((address_space(3))) void*)l, 16, 0, 0);
}

// ---------- transpose tile body: src [R][C] f32 (+e offset) -> dst [C][R] bf16
__device__ __forceinline__ void transpose_tile(const float* __restrict__ s,
                                               u16* __restrict__ d, int R, int C,
                                               int tileIdx) {
  __shared__ u16 tile[64][66];
  int tilesC = C >> 6;
  int bR = (tileIdx / tilesC) << 6;
  int bC = (tileIdx % tilesC) << 6;
  int rr = threadIdx.x >> 4;
  int cc = (threadIdx.x & 15) << 2;
#pragma unroll
  for (int i = 0; i < 4; ++i) {
    int r = (i << 4) + rr;
    float4 v = *(const float4*)(s + (size_t)(bR + r) * C + bC + cc);
    *(uint32_t*)&tile[r][cc]     = pack_bf2(v.x, v.y);
    *(uint32_t*)&tile[r][cc + 2] = pack_bf2(v.z, v.w);
  }
  __syncthreads();
  int c0 = threadIdx.x >> 5;
  int j  = (threadIdx.x & 31) << 1;
#pragma unroll
  for (int i = 0; i < 8; ++i) {
    int c = (i << 3) + c0;
    uint32_t v = (uint32_t)tile[j][c] | ((uint32_t)tile[j + 1][c] << 16);
    *(uint32_t*)(&d[(size_t)(bC + c) * R + bR + j]) = v;
  }
}

// ---------- fused prep: W1 transpose | W2 transpose | router
__global__ void k_prep(const float* __restrict__ W1, u16* __restrict__ W1T,
                       const float* __restrict__ W2, u16* __restrict__ W2T,
                       const float* __restrict__ x, const float* __restrict__ Wr,
                       const float* __restrict__ br, int* __restrict__ sel_idx,
                       float* __restrict__ sel_w, int Ntok) {
  int b = blockIdx.x;
  if (b < 2048) {
    int e = b >> 8, t = b & 255;
    transpose_tile(W1 + (size_t)e * DM * DFF, W1T + (size_t)e * DM * DFF, DM, DFF, t);
    return;
  }
  if (b < 4096) {
    int e = (b - 2048) >> 8, t = (b - 2048) & 255;
    transpose_tile(W2 + (size_t)e * DFF * DM, W2T + (size_t)e * DFF * DM, DFF, DM, t);
    return;
  }
  int rb = b - 4096;
  int wid = threadIdx.x >> 6;
  int lane = threadIdx.x & 63;
  int tok = (rb << 2) + wid;
  if (tok >= Ntok) return;
  const float4* xr = (const float4*)(x + (size_t)tok * DM);
  float4 x0 = xr[lane * 2], x1 = xr[lane * 2 + 1];
  float logit[NEXP];
#pragma unroll
  for (int e = 0; e < NEXP; ++e) {
    const float4* wr = (const float4*)(Wr + e * DM);
    float4 w0 = wr[lane * 2], w1 = wr[lane * 2 + 1];
    float p = x0.x * w0.x + x0.y * w0.y + x0.z * w0.z + x0.w * w0.w
            + x1.x * w1.x + x1.y * w1.y + x1.z * w1.z + x1.w * w1.w;
#pragma unroll
    for (int off = 32; off; off >>= 1) p += __shfl_xor(p, off, 64);
    logit[e] = p + br[e];
  }
  if (lane == 0) {
    float mx = logit[0];
#pragma unroll
    for (int e = 1; e < NEXP; ++e) mx = fmaxf(mx, logit[e]);
    float pr[NEXP];
#pragma unroll
    for (int e = 0; e < NEXP; ++e) pr[e] = __expf(logit[e] - mx);
    int i0 = 0;
#pragma unroll
    for (int e = 1; e < NEXP; ++e) if (pr[e] > pr[i0]) i0 = e;
    int i1 = -1;
#pragma unroll
    for (int e = 0; e < NEXP; ++e) {
      if (e == i0) continue;
      if (i1 < 0 || pr[e] > pr[i1]) i1 = e;
    }
    float s2 = pr[i0] + pr[i1];
    sel_idx[tok * 2]     = i0;
    sel_idx[tok * 2 + 1] = i1;
    sel_w[tok * 2]       = pr[i0] / s2;
    sel_w[tok * 2 + 1]   = pr[i1] / s2;
  }
}

// ---------- scatter (1 block, ballot-based), 128-row tile granularity
__global__ void k_scatter(const int* __restrict__ sel_idx, const float* __restrict__ sel_w,
                          int npairs, int* __restrict__ row_token, float* __restrict__ row_w,
                          int* __restrict__ pos_of, int* __restrict__ tileMeta,
                          int* __restrict__ gMeta) {
  __shared__ int cnt[NEXP], offs[NEXP], cur[NEXP];
  int tid = threadIdx.x;
  int lane = tid & 63;
  if (tid < NEXP) { cnt[tid] = 0; cur[tid] = 0; }
  __syncthreads();
  for (int p = tid; p < npairs; p += blockDim.x) {
    int e = sel_idx[p];
#pragma unroll
    for (int ex = 0; ex < NEXP; ++ex) {
      unsigned long long m = __ballot(e == ex);
      if (lane == 0 && m) atomicAdd(&cnt[ex], __popcll(m));
    }
  }
  __syncthreads();
  if (tid == 0) {
    int o = 0, nmt = 0;
    for (int e = 0; e < NEXP; ++e) {
      offs[e] = o;
      int c = cnt[e];
      int nt = (c + 127) >> 7;
      for (int t = 0; t < nt; ++t) {
        tileMeta[nmt * 3 + 0] = o + t * 128;
        tileMeta[nmt * 3 + 1] = o + c;
        tileMeta[nmt * 3 + 2] = e;
        ++nmt;
      }
      o += c;
    }
    gMeta[0] = nmt;
  }
  __syncthreads();
  for (int p = tid; p < npairs; p += blockDim.x) {
    int e = sel_idx[p];
    int pos = 0;
#pragma unroll
    for (int ex = 0; ex < NEXP; ++ex) {
      unsigned long long m = __ballot(e == ex);
      if (m) {
        int leader = __ffsll((long long)m) - 1;
        int base = 0;
        if (lane == leader) base = atomicAdd(&cur[ex], __popcll(m));
        base = __shfl(base, leader, 64);
        if (e == ex)
          pos = offs[ex] + base + __popcll(m & ((1ull << lane) - 1ull));
      }
    }
    row_token[pos] = p >> 1;
    row_w[pos] = sel_w[p];
    pos_of[p] = pos;
  }
}

// ---------- gather selected token rows -> bf16
__global__ void k_gather(const float* __restrict__ x, const int* __restrict__ row_token,
                         u16* __restrict__ Xg, int npairs) {
  int pos = (blockIdx.x << 2) + (threadIdx.x >> 6);
  int lane = threadIdx.x & 63;
  if (pos >= npairs) return;
  int tok = row_token[pos];
  const float4* src = (const float4*)(x + (size_t)tok * DM);
  float4 a = src[lane * 2], b = src[lane * 2 + 1];
  uint4 o;
  o.x = pack_bf2(a.x, a.y);
  o.y = pack_bf2(a.z, a.w);
  o.z = pack_bf2(b.x, b.y);
  o.w = pack_bf2(b.z, b.w);
  ((uint4*)(Xg + (size_t)pos * DM))[lane] = o;
}

// ---------- 128x128 grouped GEMM (R3-proven core), BK=32, 3-slot ring,
// counted vmcnt(4), 1 barrier/K-tile, 256 thr / 4 waves (2x2), 48KB -> 3 blocks/CU.
// NEW: 8xSN super-tiled wg->(mt,nt) mapping + XCD chunking for L2 operand reuse.
// Out: bf16 [NSPLIT][npairs][NFULL] (split stride pstride u16 elems)
template <int NFULL, int KTOT, int NSPLIT, bool GELU, bool SCALE>
__launch_bounds__(256)
__global__ void k_gemm(const u16* __restrict__ A, const u16* __restrict__ BT,
                       const float* __restrict__ bias, const float* __restrict__ row_w,
                       u16* __restrict__ Out, size_t pstride,
                       const int* __restrict__ tileMeta, const int* __restrict__ gMeta,
                       int maxmt) {
  constexpr int NTN = NFULL / 128;
  constexpr int SN  = (NTN >= 8) ? 8 : NTN;   // super width (nt)
  constexpr int NSN = NTN / SN;
  constexpr int SUPER = 8 * SN;               // blocks per super (8 mt x SN nt)
  constexpr int KCH = KTOT / NSPLIT;
  constexpr int NK  = KCH / 32;

  // slot: A 128x64B (8KB) @0, B 8KB @8192 ; 3 slots = 48KB
  __shared__ __align__(16) u16 smem[24576];

  int NB = gridDim.x;
  int bid = blockIdx.x;
  int wg = ((NB & 7) == 0) ? ((bid & 7) * (NB >> 3) + (bid >> 3)) : bid;  // XCD chunking
  // super-tile decode
  int s = wg / SUPER, l = wg % SUPER;
  int nsm = maxmt >> 3;                        // supers per (split) row-dim; maxmt % 8 == 0
  int split = s / (nsm * NSN);
  int srem  = s % (nsm * NSN);
  int sm = srem / NSN, sn = srem % NSN;
  int mt = sm * 8 + l / SN;
  int nt = sn * SN + l % SN;
  if (mt >= gMeta[0]) return;
  int posStart = tileMeta[mt * 3 + 0];
  int segEnd   = tileMeta[mt * 3 + 1];
  int e        = tileMeta[mt * 3 + 2];

  int tid = threadIdx.x, lane = tid & 63, wid = tid >> 6;
  int wm = wid >> 1, wn = wid & 1;             // 2 x 2 waves; wave tile 64 x 64

  const u16* Ab = A + (size_t)split * KCH;
  const u16* Bb = BT + ((size_t)e * NFULL + (size_t)nt * 128) * KTOT + (size_t)split * KCH;

  // staging: instr i covers rows i*64 + wid*16 + (lane>>2); chunk lane&3 of 64B row.
  // pre-swizzled source chunk = c ^ ((row>>1)&3)  (2-way max on read = free, R7-verified 0 conflicts)
  int l4 = lane >> 2, c4 = lane & 3;
  const u16* aS[2];
  const u16* bS[2];
#pragma unroll
  for (int i = 0; i < 2; ++i) {
    int r = i * 64 + wid * 16 + l4;
    int g = posStart + r; if (g >= segEnd) g = segEnd - 1;
    int cs = c4 ^ ((r >> 1) & 3);
    aS[i] = Ab + (size_t)g * KTOT + cs * 8;
    bS[i] = Bb + (size_t)r * KTOT + cs * 8;
  }

  auto stage = [&](int kt, int slot) {
    u16* as = smem + slot * 8192;
    u16* bs = as + 4096;
#pragma unroll
    for (int i = 0; i < 2; ++i) {
      async16(aS[i] + kt * 32, as + i * 2048 + wid * 512);
      async16(bS[i] + kt * 32, bs + i * 2048 + wid * 512);
    }
  };

  f32x4 acc[4][4] = {};

  stage(0, 0);
  stage(1, 1);
  int bufC = 0, bufS = 2;
#pragma unroll 1
  for (int t = 0; t < NK; ++t) {
    if (t + 1 < NK) asm volatile("s_waitcnt vmcnt(4)" ::: "memory");
    else            asm volatile("s_waitcnt vmcnt(0)" ::: "memory");
    __builtin_amdgcn_s_barrier();
    asm volatile("" ::: "memory");
    if (t + 2 < NK) { stage(t + 2, bufS); bufS = (bufS == 2) ? 0 : bufS + 1; }
    const char* AsB = (const char*)(smem + bufC * 8192);
    const char* BsB = AsB + 8192;
    int kb = (lane >> 4) << 4;
    bf16x8 av[4], bv[4];
#pragma unroll
    for (int mi = 0; mi < 4; ++mi) {
      int row = (wm << 6) + (mi << 4) + (lane & 15);
      av[mi] = *(const bf16x8*)(AsB + row * 64 + (kb ^ (((row >> 1) & 3) << 4)));
    }
#pragma unroll
    for (int ni = 0; ni < 4; ++ni) {
      int row = (wn << 6) + (ni << 4) + (lane & 15);
      bv[ni] = *(const bf16x8*)(BsB + row * 64 + (kb ^ (((row >> 1) & 3) << 4)));
    }
    __builtin_amdgcn_s_setprio(1);
#pragma unroll
    for (int mi = 0; mi < 4; ++mi)
#pragma unroll
      for (int ni = 0; ni < 4; ++ni)
        acc[mi][ni] = __builtin_amdgcn_mfma_f32_16x16x32_bf16(av[mi], bv[ni], acc[mi][ni], 0, 0, 0);
    __builtin_amdgcn_s_setprio(0);
    bufC = (bufC == 2) ? 0 : bufC + 1;
  }

  // ---------- epilogue: frag -> LDS (pad 136, 16B-aligned rows) -> coalesced 16B stores
  __syncthreads();
  u16* Cs = smem;   // 128 x 136 u16 = 34KB <= 48KB
  int laneCol = lane & 15;
  int laneRow4 = (lane >> 4) << 2;
  const float* biasE = bias + (size_t)e * NFULL;
  u16* OutS = Out + (size_t)split * pstride;
#pragma unroll
  for (int mi = 0; mi < 4; ++mi) {
#pragma unroll
    for (int j = 0; j < 4; ++j) {
      int r = (wm << 6) + (mi << 4) + laneRow4 + j;
      int m = posStart + r;
      int mc = m < segEnd ? m : segEnd - 1;
      float w = 1.0f;
      if constexpr (SCALE) w = row_w[mc];
#pragma unroll
      for (int ni = 0; ni < 4; ++ni) {
        int cl = (wn << 6) + (ni << 4) + laneCol;
        float v = acc[mi][ni][j];
        if (split == 0) v += biasE[nt * 128 + cl];
        if constexpr (GELU) v = gelu_tanh(v);
        if constexpr (SCALE) v *= w;
        Cs[r * 136 + cl] = f2bf(v);
      }
    }
  }
  __syncthreads();
  int r0 = tid >> 4, q = tid & 15;
#pragma unroll
  for (int i = 0; i < 8; ++i) {
    int r = (i << 4) + r0;
    if (posStart + r < segEnd)
      *((uint4*)(OutS + (size_t)(posStart + r) * NFULL + (nt << 7)) + q) =
          ((uint4*)(Cs + (size_t)r * 136))[q];
  }
}

// ---------- combine: out[tok] = sum over splits x {pos0,pos1} of bf16 partials
template <int NSPLIT>
__global__ void k_combine(const u16* __restrict__ P, size_t pstride,
                          const int* __restrict__ pos_of, float* __restrict__ out, int Ntok) {
  int tok = (blockIdx.x << 2) + (threadIdx.x >> 6);
  int lane = threadIdx.x & 63;
  if (tok >= Ntok) return;
  int p0 = pos_of[tok * 2], p1 = pos_of[tok * 2 + 1];
  float s[8] = {};
#pragma unroll
  for (int sp = 0; sp < NSPLIT; ++sp) {
    bf16x8 a = ((const bf16x8*)(P + sp * pstride + (size_t)p0 * DM))[lane];
    bf16x8 b = ((const bf16x8*)(P + sp * pstride + (size_t)p1 * DM))[lane];
#pragma unroll
    for (int i = 0; i < 8; ++i) s[i] += (float)a[i] + (float)b[i];
  }
  float4* o = (float4*)(out + (size_t)tok * DM + lane * 8);
  o[0] = make_float4(s[0], s[1], s[2], s[3]);
  o[1] = make_float4(s[4], s[5], s[6], s[7]);
}

extern "C" void kernel_launch(void* const* d_in, const int* in_sizes, int n_in,
                              void* d_out, int out_size, void* d_ws, size_t ws_size,
                              hipStream_t stream) {
  const float* x  = (const float*)d_in[0];
  const float* Wr = (const float*)d_in[1];
  const float* br = (const float*)d_in[2];
  const float* W1 = (const float*)d_in[3];
  const float* b1 = (const float*)d_in[4];
  const float* W2 = (const float*)d_in[5];
  const float* b2 = (const float*)d_in[6];
  float* out = (float*)d_out;

  int Ntok = in_sizes[0] / DM;          // 4096
  int npairs = Ntok * 2;                // 8192
  int maxmt = npairs / 128 + NEXP;      // 72 (multiple of 8)
  size_t pstride = (size_t)npairs * DM; // u16 elems per split

  char* p = (char*)d_ws;
  u16* W1T = (u16*)p;  p += (size_t)NEXP * DFF * DM * 2;
  u16* W2T = (u16*)p;  p += (size_t)NEXP * DM * DFF * 2;
  u16* Xg  = (u16*)p;  p += (size_t)npairs * DM * 2;
  u16* H   = (u16*)p;  p += (size_t)npairs * DFF * 2;
  u16* Part = (u16*)p; p += 2 * pstride * 2;          // [2][npairs][DM] bf16
  int* sel_idx   = (int*)p;   p += (size_t)npairs * 4;
  float* sel_w   = (float*)p; p += (size_t)npairs * 4;
  int* pos_of    = (int*)p;   p += (size_t)npairs * 4;
  int* row_token = (int*)p;   p += (size_t)npairs * 4;
  float* row_w   = (float*)p; p += (size_t)npairs * 4;
  int* tileMeta  = (int*)p;   p += (size_t)(maxmt * 3 + 16) * 4;
  int* gMeta     = (int*)p;   p += 64;

  k_prep<<<dim3(4096 + Ntok / 4), 256, 0, stream>>>(W1, W1T, W2, W2T, x, Wr, br,
                                                    sel_idx, sel_w, Ntok);
  k_scatter<<<dim3(1), 1024, 0, stream>>>(sel_idx, sel_w, npairs, row_token, row_w,
                                          pos_of, tileMeta, gMeta);
  k_gather<<<dim3(npairs / 4), 256, 0, stream>>>(x, row_token, Xg, npairs);
  // GEMM1: H = gelu(Xg * W1T + b1), 128x128, grid 72*16 = 1152
  k_gemm<DFF, DM, 1, true, false>
      <<<dim3(maxmt * (DFF / 128)), 256, 0, stream>>>(
          Xg, W1T, b1, nullptr, H, 0, tileMeta, gMeta, maxmt);
  // GEMM2: Part[s] = (H_s * W2T_s + (s==0)*b2) * row_w, split-K=2, grid 72*4*2 = 576
  k_gemm<DM, DFF, 2, false, true>
      <<<dim3(maxmt * (DM / 128) * 2), 256, 0, stream>>>(
          H, W2T, b2, row_w, Part, pstride, tileMeta, gMeta, maxmt);
  k_combine<2><<<dim3(Ntok / 4), 256, 0, stream>>>(Part, pstride, pos_of, out, Ntok);
}